// Round 3
// baseline (2006.503 us; speedup 1.0000x reference)
//
#include <hip/hip_runtime.h>
#include <hip/hip_bf16.h>

#define TOK 2048      // B*S
#define DIM 1024      // D
#define HID 4096      // H
#define NE  8         // experts

typedef short bf16x8 __attribute__((ext_vector_type(8)));
typedef float f32x4 __attribute__((ext_vector_type(4)));
typedef unsigned short ushort_t;
typedef unsigned int uint_t;

__device__ __forceinline__ ushort_t f2bf(float f) {
  uint_t b = __float_as_uint(f);
  uint_t r = (b + 0x7FFFu + ((b >> 16) & 1u)) >> 16;
  return (ushort_t)r;
}
__device__ __forceinline__ float bf2f(ushort_t u) {
  return __uint_as_float(((uint_t)u) << 16);
}

// ---------------- router ----------------
__global__ void router_kernel(const float* __restrict__ x,
                              const float* __restrict__ rw,
                              const float* __restrict__ rb,
                              int* __restrict__ counts,
                              float* __restrict__ tok_ss,
                              int* __restrict__ top_e,
                              float* __restrict__ top_w) {
  const int t = blockIdx.x;
  const int lane = threadIdx.x;
  float acc[NE];
#pragma unroll
  for (int e = 0; e < NE; ++e) acc[e] = 0.f;
  const float* xr = x + (size_t)t * DIM;
  for (int d = lane; d < DIM; d += 64) {
    float xv = xr[d];
    const float* w = rw + (size_t)d * NE;
#pragma unroll
    for (int e = 0; e < NE; ++e) acc[e] += xv * w[e];
  }
#pragma unroll
  for (int e = 0; e < NE; ++e) {
    float v = acc[e];
#pragma unroll
    for (int off = 32; off > 0; off >>= 1) v += __shfl_down(v, off, 64);
    acc[e] = v;
  }
  if (lane == 0) {
    float sc[NE];
    float ss = 0.f;
#pragma unroll
    for (int e = 0; e < NE; ++e) {
      float lg = acc[e] + rb[e];
      ss += lg * lg;
      sc[e] = 1.f / (1.f + expf(-lg));
    }
    tok_ss[t] = ss;
    int i0 = 0;
#pragma unroll
    for (int e = 1; e < NE; ++e) if (sc[e] > sc[i0]) i0 = e;
    int i1 = (i0 == 0) ? 1 : 0;
#pragma unroll
    for (int e = 0; e < NE; ++e) if (e != i0 && sc[e] > sc[i1]) i1 = e;
    float s0 = sc[i0], s1 = sc[i1];
    float inv = 1.f / (s0 + s1 + 1e-6f);
    top_e[t * 2 + 0] = i0;
    top_e[t * 2 + 1] = i1;
    top_w[t * 2 + 0] = s0 * inv;
    top_w[t * 2 + 1] = s1 * inv;
    atomicAdd(&counts[i0], 1);
    atomicAdd(&counts[i1], 1);
  }
}

__global__ void zero_kernel(int* __restrict__ counts) {
  if (threadIdx.x < NE) counts[threadIdx.x] = 0;
}

__global__ void scan_kernel(const int* __restrict__ counts,
                            int* __restrict__ offsets,
                            int* __restrict__ fill) {
  if (threadIdx.x == 0) {
    int o = 0;
    for (int e = 0; e < NE; ++e) { offsets[e] = o; o += counts[e]; fill[e] = 0; }
    offsets[NE] = o;
  }
}

__global__ void assign_kernel(const int* __restrict__ top_e,
                              const float* __restrict__ top_w,
                              const int* __restrict__ offsets,
                              int* __restrict__ fill,
                              int* __restrict__ list_tok,
                              float* __restrict__ list_w,
                              int* __restrict__ pair_pos) {
  int i = blockIdx.x * blockDim.x + threadIdx.x;
  if (i >= TOK * 2) return;
  int e = top_e[i];
  int pos = atomicAdd(&fill[e], 1);
  int idx = offsets[e] + pos;
  list_tok[idx] = i >> 1;
  list_w[idx] = top_w[i];
  pair_pos[i] = idx;
}

__global__ void aux_kernel(const float* __restrict__ tok_ss, float* __restrict__ out_aux) {
  __shared__ float sm[256];
  float s = 0.f;
  for (int t = threadIdx.x; t < TOK; t += 256) s += tok_ss[t];
  sm[threadIdx.x] = s;
  __syncthreads();
  for (int w = 128; w > 0; w >>= 1) {
    if (threadIdx.x < w) sm[threadIdx.x] += sm[threadIdx.x + w];
    __syncthreads();
  }
  if (threadIdx.x == 0) *out_aux = 0.01f * sm[0] / (float)(TOK * NE);
}

// ---------------- conversions ----------------
__global__ void convx_kernel(const float* __restrict__ x,
                             ushort_t* __restrict__ xhi, ushort_t* __restrict__ xlo) {
  int i = blockIdx.x * 256 + threadIdx.x;
  float4 v = ((const float4*)x)[i];
  ushort4 h, l;
  h.x = f2bf(v.x); l.x = f2bf(v.x - bf2f(h.x));
  h.y = f2bf(v.y); l.y = f2bf(v.y - bf2f(h.y));
  h.z = f2bf(v.z); l.z = f2bf(v.z - bf2f(h.z));
  h.w = f2bf(v.w); l.w = f2bf(v.w - bf2f(h.w));
  ((ushort4*)xhi)[i] = h;
  ((ushort4*)xlo)[i] = l;
}

// w12 [E][D][2H] f32 -> w1t [E][H][D], w2t [E][H][D] bf16 (transpose)
__global__ __launch_bounds__(256)
void convw12_kernel(const float* __restrict__ w12,
                    ushort_t* __restrict__ w1t, ushort_t* __restrict__ w2t) {
  __shared__ float tile[64][65];
  const int n0 = blockIdx.x * 64;
  const int d0 = blockIdx.y * 64;
  const int e  = blockIdx.z;
  const int tid = threadIdx.x;
  const float* src = w12 + ((size_t)e * DIM) * (2 * HID);
#pragma unroll
  for (int i = 0; i < 4; ++i) {
    int u = tid + i * 256;
    int dr = u >> 4, c4 = u & 15;
    float4 v = *(const float4*)&src[(size_t)(d0 + dr) * (2 * HID) + n0 + c4 * 4];
    tile[dr][c4 * 4 + 0] = v.x;
    tile[dr][c4 * 4 + 1] = v.y;
    tile[dr][c4 * 4 + 2] = v.z;
    tile[dr][c4 * 4 + 3] = v.w;
  }
  __syncthreads();
  ushort_t* dst;
  size_t nbase;
  if (n0 < HID) { dst = w1t; nbase = (size_t)e * HID + n0; }
  else          { dst = w2t; nbase = (size_t)e * HID + (n0 - HID); }
#pragma unroll
  for (int i = 0; i < 4; ++i) {
    int u = tid + i * 256;
    int nr = u >> 4, d4 = u & 15;
    ushort4 o;
    o.x = f2bf(tile[d4 * 4 + 0][nr]);
    o.y = f2bf(tile[d4 * 4 + 1][nr]);
    o.z = f2bf(tile[d4 * 4 + 2][nr]);
    o.w = f2bf(tile[d4 * 4 + 3][nr]);
    *(ushort4*)&dst[(nbase + nr) * DIM + d0 + d4 * 4] = o;
  }
}

// w3 [E][H][D] f32 -> w3t [E][D][H] bf16 (transpose)
__global__ __launch_bounds__(256)
void convw3_kernel(const float* __restrict__ w3, ushort_t* __restrict__ w3t) {
  __shared__ float tile[64][65];
  const int d0 = blockIdx.x * 64;
  const int h0 = blockIdx.y * 64;
  const int e  = blockIdx.z;
  const int tid = threadIdx.x;
  const float* src = w3 + ((size_t)e * HID) * DIM;
#pragma unroll
  for (int i = 0; i < 4; ++i) {
    int u = tid + i * 256;
    int hr = u >> 4, c4 = u & 15;
    float4 v = *(const float4*)&src[(size_t)(h0 + hr) * DIM + d0 + c4 * 4];
    tile[hr][c4 * 4 + 0] = v.x;
    tile[hr][c4 * 4 + 1] = v.y;
    tile[hr][c4 * 4 + 2] = v.z;
    tile[hr][c4 * 4 + 3] = v.w;
  }
  __syncthreads();
#pragma unroll
  for (int i = 0; i < 4; ++i) {
    int u = tid + i * 256;
    int dr = u >> 4, h4 = u & 15;
    ushort4 o;
    o.x = f2bf(tile[h4 * 4 + 0][dr]);
    o.y = f2bf(tile[h4 * 4 + 1][dr]);
    o.z = f2bf(tile[h4 * 4 + 2][dr]);
    o.w = f2bf(tile[h4 * 4 + 3][dr]);
    *(ushort4*)&w3t[((size_t)e * DIM + d0 + dr) * HID + h0 + h4 * 4] = o;
  }
}

// ---------------- GEMM1: h = silu(X@W1)*(X@W2), A hi/lo, BM=64 BN=128 BK=64 ----------------
__global__ __launch_bounds__(256)
void gemm1_mfma(const ushort_t* __restrict__ xhi, const ushort_t* __restrict__ xlo,
                const ushort_t* __restrict__ w1t, const ushort_t* __restrict__ w2t,
                const int* __restrict__ offsets, const int* __restrict__ list_tok,
                ushort_t* __restrict__ hhi) {
  __shared__ __align__(16) ushort_t Ah[64 * 64];
  __shared__ __align__(16) ushort_t Al[64 * 64];
  __shared__ __align__(16) ushort_t B1s[128 * 64];
  __shared__ __align__(16) ushort_t B2s[128 * 64];
  __shared__ int stok[64];

  const int e = blockIdx.z;
  const int rt = blockIdx.x;              // row-tile fastest: co-dispatch shares B panel
  const int rowstart = offsets[e] + rt * 64;
  const int rowend = offsets[e + 1];
  if (rowstart >= rowend) return;
  const int n0 = blockIdx.y * 128;
  const int tid = threadIdx.x;
  const int lane = tid & 63, wid = tid >> 6;
  const int wm = wid >> 1, wn = wid & 1;
  const int lr = lane & 15, kh = lane >> 4;

  if (tid < 64) {
    int r = rowstart + tid;
    stok[tid] = list_tok[r < rowend ? r : rowstart];
  }
  __syncthreads();

  // staging: slot = tid + 256*i -> (row = slot>>3, seg = tid&7); swizzle seg^=(row&7)
  const int ar0 = tid >> 3, sg = tid & 7;
  const int ar1 = ar0 + 32;
  const size_t asrc0 = (size_t)stok[ar0] * DIM + sg * 8;
  const size_t asrc1 = (size_t)stok[ar1] * DIM + sg * 8;
  const int adst0 = ar0 * 64 + ((sg ^ (ar0 & 7)) * 8);
  const int adst1 = adst0 + 32 * 64;      // (ar1&7)==(ar0&7)
  const ushort_t* w1b = w1t + ((size_t)e * HID + n0) * DIM;
  const ushort_t* w2b = w2t + ((size_t)e * HID + n0) * DIM;
  const size_t bsrc0 = (size_t)ar0 * DIM + sg * 8;

  f32x4 acc1[2][4], acc2[2][4];
#pragma unroll
  for (int mi = 0; mi < 2; ++mi)
#pragma unroll
    for (int nj = 0; nj < 4; ++nj) {
      acc1[mi][nj] = (f32x4){0.f, 0.f, 0.f, 0.f};
      acc2[mi][nj] = (f32x4){0.f, 0.f, 0.f, 0.f};
    }

  int aoff[2][2], boff[2][4];
#pragma unroll
  for (int q = 0; q < 2; ++q) {
    int seg = ((q * 4 + kh) ^ (lr & 7)) * 8;
#pragma unroll
    for (int mi = 0; mi < 2; ++mi) aoff[q][mi] = (wm * 32 + mi * 16 + lr) * 64 + seg;
#pragma unroll
    for (int nj = 0; nj < 4; ++nj) boff[q][nj] = (wn * 64 + nj * 16 + lr) * 64 + seg;
  }

  uint4 rh0, rh1, rl0, rl1, rb1[4], rb2[4];
#define G1_LOAD(K0) do { \
    rh0 = *(const uint4*)&xhi[asrc0 + (K0)]; \
    rh1 = *(const uint4*)&xhi[asrc1 + (K0)]; \
    rl0 = *(const uint4*)&xlo[asrc0 + (K0)]; \
    rl1 = *(const uint4*)&xlo[asrc1 + (K0)]; \
    _Pragma("unroll") \
    for (int i = 0; i < 4; ++i) { \
      rb1[i] = *(const uint4*)&w1b[bsrc0 + (size_t)(32 * i) * DIM + (K0)]; \
      rb2[i] = *(const uint4*)&w2b[bsrc0 + (size_t)(32 * i) * DIM + (K0)]; \
    } } while (0)

  const int NK = DIM / 64;
  G1_LOAD(0);
#pragma unroll 1
  for (int step = 0; step < NK; ++step) {
    *(uint4*)&Ah[adst0] = rh0;  *(uint4*)&Ah[adst1] = rh1;
    *(uint4*)&Al[adst0] = rl0;  *(uint4*)&Al[adst1] = rl1;
#pragma unroll
    for (int i = 0; i < 4; ++i) {
      *(uint4*)&B1s[adst0 + 32 * 64 * i] = rb1[i];
      *(uint4*)&B2s[adst0 + 32 * 64 * i] = rb2[i];
    }
    __syncthreads();
    if (step + 1 < NK) G1_LOAD((size_t)(step + 1) * 64);
#pragma unroll
    for (int q = 0; q < 2; ++q) {
      bf16x8 a_h[2], a_l[2], b1f[4], b2f[4];
#pragma unroll
      for (int mi = 0; mi < 2; ++mi) {
        a_h[mi] = *(bf16x8*)&Ah[aoff[q][mi]];
        a_l[mi] = *(bf16x8*)&Al[aoff[q][mi]];
      }
#pragma unroll
      for (int nj = 0; nj < 4; ++nj) {
        b1f[nj] = *(bf16x8*)&B1s[boff[q][nj]];
        b2f[nj] = *(bf16x8*)&B2s[boff[q][nj]];
      }
#pragma unroll
      for (int mi = 0; mi < 2; ++mi)
#pragma unroll
        for (int nj = 0; nj < 4; ++nj) {
          acc1[mi][nj] = __builtin_amdgcn_mfma_f32_16x16x32_bf16(a_h[mi], b1f[nj], acc1[mi][nj], 0, 0, 0);
          acc1[mi][nj] = __builtin_amdgcn_mfma_f32_16x16x32_bf16(a_l[mi], b1f[nj], acc1[mi][nj], 0, 0, 0);
          acc2[mi][nj] = __builtin_amdgcn_mfma_f32_16x16x32_bf16(a_h[mi], b2f[nj], acc2[mi][nj], 0, 0, 0);
          acc2[mi][nj] = __builtin_amdgcn_mfma_f32_16x16x32_bf16(a_l[mi], b2f[nj], acc2[mi][nj], 0, 0, 0);
        }
    }
    __syncthreads();
  }
#undef G1_LOAD

#pragma unroll
  for (int mi = 0; mi < 2; ++mi)
#pragma unroll
    for (int nj = 0; nj < 4; ++nj)
#pragma unroll
      for (int r = 0; r < 4; ++r) {
        int gr = rowstart + wm * 32 + mi * 16 + kh * 4 + r;
        if (gr < rowend) {
          int col = n0 + wn * 64 + nj * 16 + lr;
          float v1 = acc1[mi][nj][r], v2 = acc2[mi][nj][r];
          float hv = (v1 / (1.f + expf(-v1))) * v2;
          hhi[(size_t)gr * HID + col] = f2bf(hv);
        }
      }
}

// ---------------- GEMM2: pairout = w * (h @ W3), BM=64 BN=128 BK=64 ----------------
__global__ __launch_bounds__(256)
void gemm2_mfma(const ushort_t* __restrict__ hhi,
                const ushort_t* __restrict__ w3t,
                const int* __restrict__ offsets, const float* __restrict__ list_w,
                ushort_t* __restrict__ pairout) {
  __shared__ __align__(16) ushort_t As[64 * 64];
  __shared__ __align__(16) ushort_t Bs[128 * 64];

  const int e = blockIdx.z;
  const int rt = blockIdx.x;
  const int rowstart = offsets[e] + rt * 64;
  const int rowend = offsets[e + 1];
  if (rowstart >= rowend) return;
  const int d0 = blockIdx.y * 128;
  const int tid = threadIdx.x;
  const int lane = tid & 63, wid = tid >> 6;
  const int wm = wid >> 1, wn = wid & 1;
  const int lr = lane & 15, kh = lane >> 4;

  const int ar0 = tid >> 3, sg = tid & 7;
  const int ar1 = ar0 + 32;
  int gr0 = rowstart + ar0; if (gr0 >= rowend) gr0 = rowstart;
  int gr1 = rowstart + ar1; if (gr1 >= rowend) gr1 = rowstart;
  const size_t asrc0 = (size_t)gr0 * HID + sg * 8;
  const size_t asrc1 = (size_t)gr1 * HID + sg * 8;
  const int adst0 = ar0 * 64 + ((sg ^ (ar0 & 7)) * 8);
  const int adst1 = adst0 + 32 * 64;
  const ushort_t* w3b = w3t + ((size_t)e * DIM + d0) * HID;
  const size_t bsrc0 = (size_t)ar0 * HID + sg * 8;

  f32x4 acc[2][4];
#pragma unroll
  for (int mi = 0; mi < 2; ++mi)
#pragma unroll
    for (int nj = 0; nj < 4; ++nj) acc[mi][nj] = (f32x4){0.f, 0.f, 0.f, 0.f};

  int aoff[2][2], boff[2][4];
#pragma unroll
  for (int q = 0; q < 2; ++q) {
    int seg = ((q * 4 + kh) ^ (lr & 7)) * 8;
#pragma unroll
    for (int mi = 0; mi < 2; ++mi) aoff[q][mi] = (wm * 32 + mi * 16 + lr) * 64 + seg;
#pragma unroll
    for (int nj = 0; nj < 4; ++nj) boff[q][nj] = (wn * 64 + nj * 16 + lr) * 64 + seg;
  }

  uint4 ra0, ra1, rb[4];
#define G2_LOAD(K0) do { \
    ra0 = *(const uint4*)&hhi[asrc0 + (K0)]; \
    ra1 = *(const uint4*)&hhi[asrc1 + (K0)]; \
    _Pragma("unroll") \
    for (int i = 0; i < 4; ++i) \
      rb[i] = *(const uint4*)&w3b[bsrc0 + (size_t)(32 * i) * HID + (K0)]; \
    } while (0)

  const int NK = HID / 64;
  G2_LOAD(0);
#pragma unroll 1
  for (int step = 0; step < NK; ++step) {
    *(uint4*)&As[adst0] = ra0;  *(uint4*)&As[adst1] = ra1;
#pragma unroll
    for (int i = 0; i < 4; ++i) *(uint4*)&Bs[adst0 + 32 * 64 * i] = rb[i];
    __syncthreads();
    if (step + 1 < NK) G2_LOAD((size_t)(step + 1) * 64);
#pragma unroll
    for (int q = 0; q < 2; ++q) {
      bf16x8 af[2], bf[4];
#pragma unroll
      for (int mi = 0; mi < 2; ++mi) af[mi] = *(bf16x8*)&As[aoff[q][mi]];
#pragma unroll
      for (int nj = 0; nj < 4; ++nj) bf[nj] = *(bf16x8*)&Bs[boff[q][nj]];
#pragma unroll
      for (int mi = 0; mi < 2; ++mi)
#pragma unroll
        for (int nj = 0; nj < 4; ++nj)
          acc[mi][nj] = __builtin_amdgcn_mfma_f32_16x16x32_bf16(af[mi], bf[nj], acc[mi][nj], 0, 0, 0);
    }
    __syncthreads();
  }
#undef G2_LOAD

#pragma unroll
  for (int mi = 0; mi < 2; ++mi)
#pragma unroll
    for (int nj = 0; nj < 4; ++nj)
#pragma unroll
      for (int r = 0; r < 4; ++r) {
        int gr = rowstart + wm * 32 + mi * 16 + kh * 4 + r;
        if (gr < rowend) {
          int col = d0 + wn * 64 + nj * 16 + lr;
          pairout[(size_t)gr * DIM + col] = f2bf(acc[mi][nj][r] * list_w[gr]);
        }
      }
}

__global__ void combine_bf(const ushort_t* __restrict__ pairout,
                           const int* __restrict__ pair_pos,
                           float* __restrict__ out) {
  int i = blockIdx.x * 256 + threadIdx.x;
  int t = i >> 8;
  int dv = i & 255;
  int p0 = pair_pos[2 * t], p1 = pair_pos[2 * t + 1];
  ushort4 a = *(const ushort4*)&pairout[(size_t)p0 * DIM + dv * 4];
  ushort4 b = *(const ushort4*)&pairout[(size_t)p1 * DIM + dv * 4];
  float4 o;
  o.x = bf2f(a.x) + bf2f(b.x);
  o.y = bf2f(a.y) + bf2f(b.y);
  o.z = bf2f(a.z) + bf2f(b.z);
  o.w = bf2f(a.w) + bf2f(b.w);
  ((float4*)out)[i] = o;
}

extern "C" void kernel_launch(void* const* d_in, const int* in_sizes, int n_in,
                              void* d_out, int out_size, void* d_ws, size_t ws_size,
                              hipStream_t stream) {
  const float* x   = (const float*)d_in[0];
  const float* rw  = (const float*)d_in[1];
  const float* rb  = (const float*)d_in[2];
  const float* w12 = (const float*)d_in[3];
  const float* w3  = (const float*)d_in[4];
  float* out = (float*)d_out;

  char* ws = (char*)d_ws;
  size_t off = 0;
  auto alloc = [&](size_t bytes) {
    void* p = ws + off;
    off = (off + bytes + 255) & ~255ULL;
    return p;
  };
  int*   counts   = (int*)alloc(NE * 4);
  int*   fill     = (int*)alloc(NE * 4);
  int*   offsets  = (int*)alloc((NE + 1) * 4);
  float* tok_ss   = (float*)alloc(TOK * 4);
  int*   top_e    = (int*)alloc(TOK * 2 * 4);
  float* top_w    = (float*)alloc(TOK * 2 * 4);
  int*   list_tok = (int*)alloc(TOK * 2 * 4);
  float* list_w   = (float*)alloc(TOK * 2 * 4);
  int*   pair_pos = (int*)alloc(TOK * 2 * 4);

  ushort_t* xhi  = (ushort_t*)alloc((size_t)TOK * DIM * 2);               // 4 MB
  ushort_t* xlo  = (ushort_t*)alloc((size_t)TOK * DIM * 2);               // 4 MB
  ushort_t* wreg = (ushort_t*)alloc((size_t)NE * DIM * 2 * HID * 2);      // 128 MB
  ushort_t* hhi  = (ushort_t*)alloc((size_t)TOK * 2 * HID * 2);           // 16 MB

  ushort_t* w1t = wreg;                                   // [E][H][D]
  ushort_t* w2t = wreg + (size_t)NE * HID * DIM;          // [E][H][D]
  ushort_t* w3t = wreg;                                   // [E][D][H], reuses w1t region after gemm1
  ushort_t* pairoutb = wreg + (size_t)NE * DIM * HID;     // 8 MB, reuses w2t region

  hipLaunchKernelGGL(zero_kernel, dim3(1), dim3(64), 0, stream, counts);
  hipLaunchKernelGGL(router_kernel, dim3(TOK), dim3(64), 0, stream,
                     x, rw, rb, counts, tok_ss, top_e, top_w);
  hipLaunchKernelGGL(scan_kernel, dim3(1), dim3(64), 0, stream, counts, offsets, fill);
  hipLaunchKernelGGL(assign_kernel, dim3((TOK * 2 + 255) / 256), dim3(256), 0, stream,
                     top_e, top_w, offsets, fill, list_tok, list_w, pair_pos);
  hipLaunchKernelGGL(aux_kernel, dim3(1), dim3(256), 0, stream,
                     tok_ss, out + (size_t)TOK * DIM);

  hipLaunchKernelGGL(convx_kernel, dim3(TOK * DIM / 4 / 256), dim3(256), 0, stream,
                     x, xhi, xlo);
  hipLaunchKernelGGL(convw12_kernel, dim3(2 * HID / 64, DIM / 64, NE), dim3(256), 0, stream,
                     w12, w1t, w2t);
  hipLaunchKernelGGL(gemm1_mfma, dim3(32, HID / 128, NE), dim3(256), 0, stream,
                     xhi, xlo, w1t, w2t, offsets, list_tok, hhi);
  hipLaunchKernelGGL(convw3_kernel, dim3(DIM / 64, HID / 64, NE), dim3(256), 0, stream,
                     w3, w3t);
  hipLaunchKernelGGL(gemm2_mfma, dim3(32, DIM / 128, NE), dim3(256), 0, stream,
                     hhi, w3t, offsets, list_w, pairoutb);
  hipLaunchKernelGGL(combine_bf, dim3(TOK * DIM / 4 / 256), dim3(256), 0, stream,
                     pairoutb, pair_pos, out);
}

// Round 4
// 739.240 us; speedup vs baseline: 2.7143x; 2.7143x over previous
//
#include <hip/hip_runtime.h>
#include <hip/hip_bf16.h>

#define TOK 2048      // B*S
#define DIM 1024      // D
#define HID 4096      // H
#define NE  8         // experts

typedef short bf16x8 __attribute__((ext_vector_type(8)));
typedef float f32x4 __attribute__((ext_vector_type(4)));
typedef unsigned short ushort_t;
typedef unsigned int uint_t;

__device__ __forceinline__ ushort_t f2bf(float f) {
  uint_t b = __float_as_uint(f);
  uint_t r = (b + 0x7FFFu + ((b >> 16) & 1u)) >> 16;
  return (ushort_t)r;
}
__device__ __forceinline__ float bf2f(ushort_t u) {
  return __uint_as_float(((uint_t)u) << 16);
}

// ---------------- router ----------------
__global__ void router_kernel(const float* __restrict__ x,
                              const float* __restrict__ rw,
                              const float* __restrict__ rb,
                              int* __restrict__ counts,
                              float* __restrict__ tok_ss,
                              int* __restrict__ top_e,
                              float* __restrict__ top_w) {
  const int t = blockIdx.x;
  const int lane = threadIdx.x;
  float acc[NE];
#pragma unroll
  for (int e = 0; e < NE; ++e) acc[e] = 0.f;
  const float* xr = x + (size_t)t * DIM;
  for (int d = lane; d < DIM; d += 64) {
    float xv = xr[d];
    const float* w = rw + (size_t)d * NE;
#pragma unroll
    for (int e = 0; e < NE; ++e) acc[e] += xv * w[e];
  }
#pragma unroll
  for (int e = 0; e < NE; ++e) {
    float v = acc[e];
#pragma unroll
    for (int off = 32; off > 0; off >>= 1) v += __shfl_down(v, off, 64);
    acc[e] = v;
  }
  if (lane == 0) {
    float sc[NE];
    float ss = 0.f;
#pragma unroll
    for (int e = 0; e < NE; ++e) {
      float lg = acc[e] + rb[e];
      ss += lg * lg;
      sc[e] = 1.f / (1.f + expf(-lg));
    }
    tok_ss[t] = ss;
    int i0 = 0;
#pragma unroll
    for (int e = 1; e < NE; ++e) if (sc[e] > sc[i0]) i0 = e;
    int i1 = (i0 == 0) ? 1 : 0;
#pragma unroll
    for (int e = 0; e < NE; ++e) if (e != i0 && sc[e] > sc[i1]) i1 = e;
    float s0 = sc[i0], s1 = sc[i1];
    float inv = 1.f / (s0 + s1 + 1e-6f);
    top_e[t * 2 + 0] = i0;
    top_e[t * 2 + 1] = i1;
    top_w[t * 2 + 0] = s0 * inv;
    top_w[t * 2 + 1] = s1 * inv;
    atomicAdd(&counts[i0], 1);
    atomicAdd(&counts[i1], 1);
  }
}

__global__ void zero_kernel(int* __restrict__ counts) {
  if (threadIdx.x < NE) counts[threadIdx.x] = 0;
}

__global__ void scan_kernel(const int* __restrict__ counts,
                            int* __restrict__ offsets,
                            int* __restrict__ fill) {
  if (threadIdx.x == 0) {
    int o = 0;
    for (int e = 0; e < NE; ++e) { offsets[e] = o; o += counts[e]; fill[e] = 0; }
    offsets[NE] = o;
  }
}

__global__ void assign_kernel(const int* __restrict__ top_e,
                              const float* __restrict__ top_w,
                              const int* __restrict__ offsets,
                              int* __restrict__ fill,
                              int* __restrict__ list_tok,
                              float* __restrict__ list_w,
                              int* __restrict__ pair_pos) {
  int i = blockIdx.x * blockDim.x + threadIdx.x;
  if (i >= TOK * 2) return;
  int e = top_e[i];
  int pos = atomicAdd(&fill[e], 1);
  int idx = offsets[e] + pos;
  list_tok[idx] = i >> 1;
  list_w[idx] = top_w[i];
  pair_pos[i] = idx;
}

__global__ void aux_kernel(const float* __restrict__ tok_ss, float* __restrict__ out_aux) {
  __shared__ float sm[256];
  float s = 0.f;
  for (int t = threadIdx.x; t < TOK; t += 256) s += tok_ss[t];
  sm[threadIdx.x] = s;
  __syncthreads();
  for (int w = 128; w > 0; w >>= 1) {
    if (threadIdx.x < w) sm[threadIdx.x] += sm[threadIdx.x + w];
    __syncthreads();
  }
  if (threadIdx.x == 0) *out_aux = 0.01f * sm[0] / (float)(TOK * NE);
}

// ---------------- conversions ----------------
__global__ void convx_kernel(const float* __restrict__ x,
                             ushort_t* __restrict__ xhi, ushort_t* __restrict__ xlo) {
  int i = blockIdx.x * 256 + threadIdx.x;
  float4 v = ((const float4*)x)[i];
  ushort4 h, l;
  h.x = f2bf(v.x); l.x = f2bf(v.x - bf2f(h.x));
  h.y = f2bf(v.y); l.y = f2bf(v.y - bf2f(h.y));
  h.z = f2bf(v.z); l.z = f2bf(v.z - bf2f(h.z));
  h.w = f2bf(v.w); l.w = f2bf(v.w - bf2f(h.w));
  ((ushort4*)xhi)[i] = h;
  ((ushort4*)xlo)[i] = l;
}

// w12 [E][D][2H] f32 -> w1t [E][H][D], w2t [E][H][D] bf16 (transpose)
__global__ __launch_bounds__(256)
void convw12_kernel(const float* __restrict__ w12,
                    ushort_t* __restrict__ w1t, ushort_t* __restrict__ w2t) {
  __shared__ float tile[64][65];
  const int n0 = blockIdx.x * 64;
  const int d0 = blockIdx.y * 64;
  const int e  = blockIdx.z;
  const int tid = threadIdx.x;
  const float* src = w12 + ((size_t)e * DIM) * (2 * HID);
#pragma unroll
  for (int i = 0; i < 4; ++i) {
    int u = tid + i * 256;
    int dr = u >> 4, c4 = u & 15;
    float4 v = *(const float4*)&src[(size_t)(d0 + dr) * (2 * HID) + n0 + c4 * 4];
    tile[dr][c4 * 4 + 0] = v.x;
    tile[dr][c4 * 4 + 1] = v.y;
    tile[dr][c4 * 4 + 2] = v.z;
    tile[dr][c4 * 4 + 3] = v.w;
  }
  __syncthreads();
  ushort_t* dst;
  size_t nbase;
  if (n0 < HID) { dst = w1t; nbase = (size_t)e * HID + n0; }
  else          { dst = w2t; nbase = (size_t)e * HID + (n0 - HID); }
#pragma unroll
  for (int i = 0; i < 4; ++i) {
    int u = tid + i * 256;
    int nr = u >> 4, d4 = u & 15;
    ushort4 o;
    o.x = f2bf(tile[d4 * 4 + 0][nr]);
    o.y = f2bf(tile[d4 * 4 + 1][nr]);
    o.z = f2bf(tile[d4 * 4 + 2][nr]);
    o.w = f2bf(tile[d4 * 4 + 3][nr]);
    *(ushort4*)&dst[(nbase + nr) * DIM + d0 + d4 * 4] = o;
  }
}

// w3 [E][H][D] f32 -> w3t [E][D][H] bf16 (transpose)
__global__ __launch_bounds__(256)
void convw3_kernel(const float* __restrict__ w3, ushort_t* __restrict__ w3t) {
  __shared__ float tile[64][65];
  const int d0 = blockIdx.x * 64;
  const int h0 = blockIdx.y * 64;
  const int e  = blockIdx.z;
  const int tid = threadIdx.x;
  const float* src = w3 + ((size_t)e * HID) * DIM;
#pragma unroll
  for (int i = 0; i < 4; ++i) {
    int u = tid + i * 256;
    int hr = u >> 4, c4 = u & 15;
    float4 v = *(const float4*)&src[(size_t)(h0 + hr) * DIM + d0 + c4 * 4];
    tile[hr][c4 * 4 + 0] = v.x;
    tile[hr][c4 * 4 + 1] = v.y;
    tile[hr][c4 * 4 + 2] = v.z;
    tile[hr][c4 * 4 + 3] = v.w;
  }
  __syncthreads();
#pragma unroll
  for (int i = 0; i < 4; ++i) {
    int u = tid + i * 256;
    int dr = u >> 4, h4 = u & 15;
    ushort4 o;
    o.x = f2bf(tile[h4 * 4 + 0][dr]);
    o.y = f2bf(tile[h4 * 4 + 1][dr]);
    o.z = f2bf(tile[h4 * 4 + 2][dr]);
    o.w = f2bf(tile[h4 * 4 + 3][dr]);
    *(ushort4*)&w3t[((size_t)e * DIM + d0 + dr) * HID + h0 + h4 * 4] = o;
  }
}

// ---------------- GEMM1 (round-2 proven structure): BM=128 BN=64 BK=32 ----------------
// grid: x = col-tile (fastest -> B-panel sharers land on same XCD), y = e*16+rt
__global__ __launch_bounds__(256)
void gemm1_mfma(const ushort_t* __restrict__ xhi, const ushort_t* __restrict__ xlo,
                const ushort_t* __restrict__ w1t, const ushort_t* __restrict__ w2t,
                const int* __restrict__ offsets, const int* __restrict__ list_tok,
                ushort_t* __restrict__ hhi) {
  __shared__ __align__(16) ushort_t Ah[128 * 40];
  __shared__ __align__(16) ushort_t Al[128 * 40];
  __shared__ __align__(16) ushort_t B1[64 * 40];
  __shared__ __align__(16) ushort_t B2[64 * 40];
  __shared__ int stok[128];

  const int e = blockIdx.y >> 4;          // 16 row-tiles of 128 per expert
  const int rt = blockIdx.y & 15;
  const int rowstart = offsets[e] + rt * 128;
  const int rowend = offsets[e + 1];
  if (rowstart >= rowend) return;
  const int h0 = blockIdx.x * 64;
  const int tid = threadIdx.x;
  const int lane = tid & 63, wid = tid >> 6;
  const int wm = wid >> 1, wn = wid & 1;
  const int lr = lane & 15, kh = lane >> 4;

  if (tid < 128) {
    int r = rowstart + tid;
    stok[tid] = list_tok[r < rowend ? r : rowstart];
  }
  __syncthreads();

  f32x4 acc1[4][2], acc2[4][2];
#pragma unroll
  for (int mi = 0; mi < 4; ++mi)
#pragma unroll
    for (int nj = 0; nj < 2; ++nj) {
      acc1[mi][nj] = (f32x4){0.f, 0.f, 0.f, 0.f};
      acc2[mi][nj] = (f32x4){0.f, 0.f, 0.f, 0.f};
    }

  const size_t wbase = ((size_t)e * HID + h0) * DIM;

  for (int k0 = 0; k0 < DIM; k0 += 32) {
#pragma unroll
    for (int i = 0; i < 2; ++i) {
      int u = tid + i * 256;
      int row = u >> 2, seg = u & 3;
      size_t src = (size_t)stok[row] * DIM + k0 + seg * 8;
      *(uint4*)&Ah[row * 40 + seg * 8] = *(const uint4*)&xhi[src];
      *(uint4*)&Al[row * 40 + seg * 8] = *(const uint4*)&xlo[src];
    }
    {
      int row = tid >> 2, seg = tid & 3;
      size_t srcoff = wbase + (size_t)row * DIM + k0 + seg * 8;
      *(uint4*)&B1[row * 40 + seg * 8] = *(const uint4*)&w1t[srcoff];
      *(uint4*)&B2[row * 40 + seg * 8] = *(const uint4*)&w2t[srcoff];
    }
    __syncthreads();

    bf16x8 a_h[4], a_l[4], b1f[2], b2f[2];
#pragma unroll
    for (int mi = 0; mi < 4; ++mi) {
      a_h[mi] = *(bf16x8*)&Ah[(wm * 64 + mi * 16 + lr) * 40 + kh * 8];
      a_l[mi] = *(bf16x8*)&Al[(wm * 64 + mi * 16 + lr) * 40 + kh * 8];
    }
#pragma unroll
    for (int nj = 0; nj < 2; ++nj) {
      b1f[nj] = *(bf16x8*)&B1[(wn * 32 + nj * 16 + lr) * 40 + kh * 8];
      b2f[nj] = *(bf16x8*)&B2[(wn * 32 + nj * 16 + lr) * 40 + kh * 8];
    }
#pragma unroll
    for (int mi = 0; mi < 4; ++mi)
#pragma unroll
      for (int nj = 0; nj < 2; ++nj) {
        acc1[mi][nj] = __builtin_amdgcn_mfma_f32_16x16x32_bf16(a_h[mi], b1f[nj], acc1[mi][nj], 0, 0, 0);
        acc1[mi][nj] = __builtin_amdgcn_mfma_f32_16x16x32_bf16(a_l[mi], b1f[nj], acc1[mi][nj], 0, 0, 0);
        acc2[mi][nj] = __builtin_amdgcn_mfma_f32_16x16x32_bf16(a_h[mi], b2f[nj], acc2[mi][nj], 0, 0, 0);
        acc2[mi][nj] = __builtin_amdgcn_mfma_f32_16x16x32_bf16(a_l[mi], b2f[nj], acc2[mi][nj], 0, 0, 0);
      }
    __syncthreads();
  }

#pragma unroll
  for (int mi = 0; mi < 4; ++mi)
#pragma unroll
    for (int nj = 0; nj < 2; ++nj)
#pragma unroll
      for (int r = 0; r < 4; ++r) {
        int row_t = wm * 64 + mi * 16 + kh * 4 + r;
        int gr = rowstart + row_t;
        if (gr < rowend) {
          int col = h0 + wn * 32 + nj * 16 + lr;
          float v1 = acc1[mi][nj][r], v2 = acc2[mi][nj][r];
          float hv = (v1 / (1.f + expf(-v1))) * v2;
          hhi[(size_t)gr * HID + col] = f2bf(hv);
        }
      }
}

// ---------------- GEMM2 (round-3 structure, grid x=col): BM=64 BN=128 BK=64 ----------------
__global__ __launch_bounds__(256)
void gemm2_mfma(const ushort_t* __restrict__ hhi,
                const ushort_t* __restrict__ w3t,
                const int* __restrict__ offsets, const float* __restrict__ list_w,
                ushort_t* __restrict__ pairout) {
  __shared__ __align__(16) ushort_t As[64 * 64];
  __shared__ __align__(16) ushort_t Bs[128 * 64];

  const int e = blockIdx.z;
  const int rt = blockIdx.y;              // y = row-tile; x = col-tile (fastest)
  const int rowstart = offsets[e] + rt * 64;
  const int rowend = offsets[e + 1];
  if (rowstart >= rowend) return;
  const int d0 = blockIdx.x * 128;
  const int tid = threadIdx.x;
  const int lane = tid & 63, wid = tid >> 6;
  const int wm = wid >> 1, wn = wid & 1;
  const int lr = lane & 15, kh = lane >> 4;

  const int ar0 = tid >> 3, sg = tid & 7;
  const int ar1 = ar0 + 32;
  int gr0 = rowstart + ar0; if (gr0 >= rowend) gr0 = rowstart;
  int gr1 = rowstart + ar1; if (gr1 >= rowend) gr1 = rowstart;
  const size_t asrc0 = (size_t)gr0 * HID + sg * 8;
  const size_t asrc1 = (size_t)gr1 * HID + sg * 8;
  const int adst0 = ar0 * 64 + ((sg ^ (ar0 & 7)) * 8);
  const int adst1 = adst0 + 32 * 64;
  const ushort_t* w3b = w3t + ((size_t)e * DIM + d0) * HID;
  const size_t bsrc0 = (size_t)ar0 * HID + sg * 8;

  f32x4 acc[2][4];
#pragma unroll
  for (int mi = 0; mi < 2; ++mi)
#pragma unroll
    for (int nj = 0; nj < 4; ++nj) acc[mi][nj] = (f32x4){0.f, 0.f, 0.f, 0.f};

  int aoff[2][2], boff[2][4];
#pragma unroll
  for (int q = 0; q < 2; ++q) {
    int seg = ((q * 4 + kh) ^ (lr & 7)) * 8;
#pragma unroll
    for (int mi = 0; mi < 2; ++mi) aoff[q][mi] = (wm * 32 + mi * 16 + lr) * 64 + seg;
#pragma unroll
    for (int nj = 0; nj < 4; ++nj) boff[q][nj] = (wn * 64 + nj * 16 + lr) * 64 + seg;
  }

  uint4 ra0, ra1, rb[4];
#define G2_LOAD(K0) do { \
    ra0 = *(const uint4*)&hhi[asrc0 + (K0)]; \
    ra1 = *(const uint4*)&hhi[asrc1 + (K0)]; \
    _Pragma("unroll") \
    for (int i = 0; i < 4; ++i) \
      rb[i] = *(const uint4*)&w3b[bsrc0 + (size_t)(32 * i) * HID + (K0)]; \
    } while (0)

  const int NK = HID / 64;
  G2_LOAD(0);
#pragma unroll 1
  for (int step = 0; step < NK; ++step) {
    *(uint4*)&As[adst0] = ra0;  *(uint4*)&As[adst1] = ra1;
#pragma unroll
    for (int i = 0; i < 4; ++i) *(uint4*)&Bs[adst0 + 32 * 64 * i] = rb[i];
    __syncthreads();
    if (step + 1 < NK) G2_LOAD((size_t)(step + 1) * 64);
#pragma unroll
    for (int q = 0; q < 2; ++q) {
      bf16x8 af[2], bf[4];
#pragma unroll
      for (int mi = 0; mi < 2; ++mi) af[mi] = *(bf16x8*)&As[aoff[q][mi]];
#pragma unroll
      for (int nj = 0; nj < 4; ++nj) bf[nj] = *(bf16x8*)&Bs[boff[q][nj]];
#pragma unroll
      for (int mi = 0; mi < 2; ++mi)
#pragma unroll
        for (int nj = 0; nj < 4; ++nj)
          acc[mi][nj] = __builtin_amdgcn_mfma_f32_16x16x32_bf16(af[mi], bf[nj], acc[mi][nj], 0, 0, 0);
    }
    __syncthreads();
  }
#undef G2_LOAD

#pragma unroll
  for (int mi = 0; mi < 2; ++mi)
#pragma unroll
    for (int nj = 0; nj < 4; ++nj)
#pragma unroll
      for (int r = 0; r < 4; ++r) {
        int gr = rowstart + wm * 32 + mi * 16 + kh * 4 + r;
        if (gr < rowend) {
          int col = d0 + wn * 64 + nj * 16 + lr;
          pairout[(size_t)gr * DIM + col] = f2bf(acc[mi][nj][r] * list_w[gr]);
        }
      }
}

__global__ void combine_bf(const ushort_t* __restrict__ pairout,
                           const int* __restrict__ pair_pos,
                           float* __restrict__ out) {
  int i = blockIdx.x * 256 + threadIdx.x;
  int t = i >> 8;
  int dv = i & 255;
  int p0 = pair_pos[2 * t], p1 = pair_pos[2 * t + 1];
  ushort4 a = *(const ushort4*)&pairout[(size_t)p0 * DIM + dv * 4];
  ushort4 b = *(const ushort4*)&pairout[(size_t)p1 * DIM + dv * 4];
  float4 o;
  o.x = bf2f(a.x) + bf2f(b.x);
  o.y = bf2f(a.y) + bf2f(b.y);
  o.z = bf2f(a.z) + bf2f(b.z);
  o.w = bf2f(a.w) + bf2f(b.w);
  ((float4*)out)[i] = o;
}

extern "C" void kernel_launch(void* const* d_in, const int* in_sizes, int n_in,
                              void* d_out, int out_size, void* d_ws, size_t ws_size,
                              hipStream_t stream) {
  const float* x   = (const float*)d_in[0];
  const float* rw  = (const float*)d_in[1];
  const float* rb  = (const float*)d_in[2];
  const float* w12 = (const float*)d_in[3];
  const float* w3  = (const float*)d_in[4];
  float* out = (float*)d_out;

  char* ws = (char*)d_ws;
  size_t off = 0;
  auto alloc = [&](size_t bytes) {
    void* p = ws + off;
    off = (off + bytes + 255) & ~255ULL;
    return p;
  };
  int*   counts   = (int*)alloc(NE * 4);
  int*   fill     = (int*)alloc(NE * 4);
  int*   offsets  = (int*)alloc((NE + 1) * 4);
  float* tok_ss   = (float*)alloc(TOK * 4);
  int*   top_e    = (int*)alloc(TOK * 2 * 4);
  float* top_w    = (float*)alloc(TOK * 2 * 4);
  int*   list_tok = (int*)alloc(TOK * 2 * 4);
  float* list_w   = (float*)alloc(TOK * 2 * 4);
  int*   pair_pos = (int*)alloc(TOK * 2 * 4);

  ushort_t* xhi  = (ushort_t*)alloc((size_t)TOK * DIM * 2);               // 4 MB
  ushort_t* xlo  = (ushort_t*)alloc((size_t)TOK * DIM * 2);               // 4 MB
  ushort_t* wreg = (ushort_t*)alloc((size_t)NE * DIM * 2 * HID * 2);      // 128 MB
  ushort_t* hhi  = (ushort_t*)alloc((size_t)TOK * 2 * HID * 2);           // 16 MB

  ushort_t* w1t = wreg;                                   // [E][H][D]
  ushort_t* w2t = wreg + (size_t)NE * HID * DIM;          // [E][H][D]
  ushort_t* w3t = wreg;                                   // [E][D][H], reuses w1t region after gemm1
  ushort_t* pairoutb = wreg + (size_t)NE * DIM * HID;     // 8 MB, reuses w2t region

  hipLaunchKernelGGL(zero_kernel, dim3(1), dim3(64), 0, stream, counts);
  hipLaunchKernelGGL(router_kernel, dim3(TOK), dim3(64), 0, stream,
                     x, rw, rb, counts, tok_ss, top_e, top_w);
  hipLaunchKernelGGL(scan_kernel, dim3(1), dim3(64), 0, stream, counts, offsets, fill);
  hipLaunchKernelGGL(assign_kernel, dim3((TOK * 2 + 255) / 256), dim3(256), 0, stream,
                     top_e, top_w, offsets, fill, list_tok, list_w, pair_pos);
  hipLaunchKernelGGL(aux_kernel, dim3(1), dim3(256), 0, stream,
                     tok_ss, out + (size_t)TOK * DIM);

  hipLaunchKernelGGL(convx_kernel, dim3(TOK * DIM / 4 / 256), dim3(256), 0, stream,
                     x, xhi, xlo);
  hipLaunchKernelGGL(convw12_kernel, dim3(2 * HID / 64, DIM / 64, NE), dim3(256), 0, stream,
                     w12, w1t, w2t);
  hipLaunchKernelGGL(gemm1_mfma, dim3(HID / 64, NE * 16), dim3(256), 0, stream,
                     xhi, xlo, w1t, w2t, offsets, list_tok, hhi);
  hipLaunchKernelGGL(convw3_kernel, dim3(DIM / 64, HID / 64, NE), dim3(256), 0, stream,
                     w3, w3t);
  hipLaunchKernelGGL(gemm2_mfma, dim3(DIM / 128, 32, NE), dim3(256), 0, stream,
                     hhi, w3t, offsets, list_w, pairoutb);
  hipLaunchKernelGGL(combine_bf, dim3(TOK * DIM / 4 / 256), dim3(256), 0, stream,
                     pairoutb, pair_pos, out);
}

// Round 5
// 518.786 us; speedup vs baseline: 3.8677x; 1.4249x over previous
//
#include <hip/hip_runtime.h>
#include <hip/hip_bf16.h>

#define TOK 2048      // B*S
#define DIM 1024      // D
#define HID 4096      // H
#define NE  8         // experts

typedef short bf16x8 __attribute__((ext_vector_type(8)));
typedef float f32x4 __attribute__((ext_vector_type(4)));
typedef unsigned short ushort_t;
typedef unsigned int uint_t;

// XOR-swizzle on 16B slots within a 64B row-payload (rows stride 80B).
// Derived: write-b32 lanes (n=4*n4+c) and read-b128 lanes (n=base+lr) both ~2-way.
#define SWZB(n) (((((n) >> 2) ^ ((n) >> 4)) & 3) << 4)

__device__ __forceinline__ ushort_t f2bf(float f) {
  uint_t b = __float_as_uint(f);
  uint_t r = (b + 0x7FFFu + ((b >> 16) & 1u)) >> 16;
  return (ushort_t)r;
}
__device__ __forceinline__ float bf2f(ushort_t u) {
  return __uint_as_float(((uint_t)u) << 16);
}

// ---------------- router ----------------
__global__ void router_kernel(const float* __restrict__ x,
                              const float* __restrict__ rw,
                              const float* __restrict__ rb,
                              int* __restrict__ counts,
                              float* __restrict__ tok_ss,
                              int* __restrict__ top_e,
                              float* __restrict__ top_w) {
  const int t = blockIdx.x;
  const int lane = threadIdx.x;
  float acc[NE];
#pragma unroll
  for (int e = 0; e < NE; ++e) acc[e] = 0.f;
  const float* xr = x + (size_t)t * DIM;
  for (int d = lane; d < DIM; d += 64) {
    float xv = xr[d];
    const float* w = rw + (size_t)d * NE;
#pragma unroll
    for (int e = 0; e < NE; ++e) acc[e] += xv * w[e];
  }
#pragma unroll
  for (int e = 0; e < NE; ++e) {
    float v = acc[e];
#pragma unroll
    for (int off = 32; off > 0; off >>= 1) v += __shfl_down(v, off, 64);
    acc[e] = v;
  }
  if (lane == 0) {
    float sc[NE];
    float ss = 0.f;
#pragma unroll
    for (int e = 0; e < NE; ++e) {
      float lg = acc[e] + rb[e];
      ss += lg * lg;
      sc[e] = 1.f / (1.f + expf(-lg));
    }
    tok_ss[t] = ss;
    int i0 = 0;
#pragma unroll
    for (int e = 1; e < NE; ++e) if (sc[e] > sc[i0]) i0 = e;
    int i1 = (i0 == 0) ? 1 : 0;
#pragma unroll
    for (int e = 0; e < NE; ++e) if (e != i0 && sc[e] > sc[i1]) i1 = e;
    float s0 = sc[i0], s1 = sc[i1];
    float inv = 1.f / (s0 + s1 + 1e-6f);
    top_e[t * 2 + 0] = i0;
    top_e[t * 2 + 1] = i1;
    top_w[t * 2 + 0] = s0 * inv;
    top_w[t * 2 + 1] = s1 * inv;
    atomicAdd(&counts[i0], 1);
    atomicAdd(&counts[i1], 1);
  }
}

__global__ void zero_kernel(int* __restrict__ counts) {
  if (threadIdx.x < NE) counts[threadIdx.x] = 0;
}

__global__ void scan_kernel(const int* __restrict__ counts,
                            int* __restrict__ offsets,
                            int* __restrict__ fill) {
  if (threadIdx.x == 0) {
    int o = 0;
    for (int e = 0; e < NE; ++e) { offsets[e] = o; o += counts[e]; fill[e] = 0; }
    offsets[NE] = o;
  }
}

__global__ void assign_kernel(const int* __restrict__ top_e,
                              const float* __restrict__ top_w,
                              const int* __restrict__ offsets,
                              int* __restrict__ fill,
                              int* __restrict__ list_tok,
                              float* __restrict__ list_w,
                              int* __restrict__ pair_pos) {
  int i = blockIdx.x * blockDim.x + threadIdx.x;
  if (i >= TOK * 2) return;
  int e = top_e[i];
  int pos = atomicAdd(&fill[e], 1);
  int idx = offsets[e] + pos;
  list_tok[idx] = i >> 1;
  list_w[idx] = top_w[i];
  pair_pos[i] = idx;
}

__global__ void aux_kernel(const float* __restrict__ tok_ss, float* __restrict__ out_aux) {
  __shared__ float sm[256];
  float s = 0.f;
  for (int t = threadIdx.x; t < TOK; t += 256) s += tok_ss[t];
  sm[threadIdx.x] = s;
  __syncthreads();
  for (int w = 128; w > 0; w >>= 1) {
    if (threadIdx.x < w) sm[threadIdx.x] += sm[threadIdx.x + w];
    __syncthreads();
  }
  if (threadIdx.x == 0) *out_aux = 0.01f * sm[0] / (float)(TOK * NE);
}

// ---------------- x f32 -> hi/lo bf16 split ----------------
__global__ void convx_kernel(const float* __restrict__ x,
                             ushort_t* __restrict__ xhi, ushort_t* __restrict__ xlo) {
  int i = blockIdx.x * 256 + threadIdx.x;
  float4 v = ((const float4*)x)[i];
  ushort4 h, l;
  h.x = f2bf(v.x); l.x = f2bf(v.x - bf2f(h.x));
  h.y = f2bf(v.y); l.y = f2bf(v.y - bf2f(h.y));
  h.z = f2bf(v.z); l.z = f2bf(v.z - bf2f(h.z));
  h.w = f2bf(v.w); l.w = f2bf(v.w - bf2f(h.w));
  ((ushort4*)xhi)[i] = h;
  ((ushort4*)xlo)[i] = l;
}

// ---------------- GEMM1: h = silu(X@W1)*(X@W2) ----------------
// BM=128 BN=64 BK=32. A: xhi/xlo staged linear (stride 40). B: w12 f32 read
// directly [k][n], converted + transpose-written to LDS [n][k] (stride 40,
// SWZB 16B-slot swizzle). grid: x=col-tile (fastest), y = e*16+rt.
__global__ __launch_bounds__(256)
void gemm1_mfma(const ushort_t* __restrict__ xhi, const ushort_t* __restrict__ xlo,
                const float* __restrict__ w12,
                const int* __restrict__ offsets, const int* __restrict__ list_tok,
                ushort_t* __restrict__ hhi) {
  __shared__ __align__(16) ushort_t Ah[128 * 40];
  __shared__ __align__(16) ushort_t Al[128 * 40];
  __shared__ __align__(16) ushort_t B1[64 * 40];
  __shared__ __align__(16) ushort_t B2[64 * 40];
  __shared__ int stok[128];

  const int e = blockIdx.y >> 4;          // 16 row-tiles of 128 per expert
  const int rt = blockIdx.y & 15;
  const int rowstart = offsets[e] + rt * 128;
  const int rowend = offsets[e + 1];
  if (rowstart >= rowend) return;
  const int h0 = blockIdx.x * 64;
  const int tid = threadIdx.x;
  const int lane = tid & 63, wid = tid >> 6;
  const int wm = wid >> 1, wn = wid & 1;
  const int lr = lane & 15, kh = lane >> 4;

  if (tid < 128) {
    int r = rowstart + tid;
    stok[tid] = list_tok[r < rowend ? r : rowstart];
  }
  __syncthreads();

  f32x4 acc1[4][2], acc2[4][2];
#pragma unroll
  for (int mi = 0; mi < 4; ++mi)
#pragma unroll
    for (int nj = 0; nj < 2; ++nj) {
      acc1[mi][nj] = (f32x4){0.f, 0.f, 0.f, 0.f};
      acc2[mi][nj] = (f32x4){0.f, 0.f, 0.f, 0.f};
    }

  // B staging ids: p = k-pair (0..15 -> k=2p,2p+1), n4*4 = col base
  const int p = tid >> 4, n4 = tid & 15;
  const float* w12e = w12 + (size_t)e * DIM * (2 * HID);
  char* B1c = (char*)B1;
  char* B2c = (char*)B2;

  // precompute b-frag byte offsets (swizzled)
  int boff[2];
#pragma unroll
  for (int nj = 0; nj < 2; ++nj) {
    int n = wn * 32 + nj * 16 + lr;
    boff[nj] = n * 80 + ((kh * 16) ^ SWZB(n));
  }

  for (int k0 = 0; k0 < DIM; k0 += 32) {
    // --- A stage (linear, stride 40) ---
#pragma unroll
    for (int i = 0; i < 2; ++i) {
      int u = tid + i * 256;
      int row = u >> 2, seg = u & 3;
      size_t src = (size_t)stok[row] * DIM + k0 + seg * 8;
      *(uint4*)&Ah[row * 40 + seg * 8] = *(const uint4*)&xhi[src];
      *(uint4*)&Al[row * 40 + seg * 8] = *(const uint4*)&xlo[src];
    }
    // --- B stage: fused f32 read + bf16 convert + transpose ---
    {
      const float* r0 = w12e + (size_t)(k0 + 2 * p) * (2 * HID) + h0 + n4 * 4;
      float4 w1a = *(const float4*)r0;
      float4 w1b = *(const float4*)(r0 + 2 * HID);
      float4 w2a = *(const float4*)(r0 + HID);
      float4 w2b = *(const float4*)(r0 + HID + 2 * HID);
      const float* p1a = (const float*)&w1a;
      const float* p1b = (const float*)&w1b;
      const float* p2a = (const float*)&w2a;
      const float* p2b = (const float*)&w2b;
#pragma unroll
      for (int c = 0; c < 4; ++c) {
        int n = n4 * 4 + c;
        int off = n * 80 + ((4 * p) ^ SWZB(n));
        *(uint_t*)(B1c + off) = (uint_t)f2bf(p1a[c]) | ((uint_t)f2bf(p1b[c]) << 16);
        *(uint_t*)(B2c + off) = (uint_t)f2bf(p2a[c]) | ((uint_t)f2bf(p2b[c]) << 16);
      }
    }
    __syncthreads();

    bf16x8 a_h[4], a_l[4], b1f[2], b2f[2];
#pragma unroll
    for (int mi = 0; mi < 4; ++mi) {
      a_h[mi] = *(bf16x8*)&Ah[(wm * 64 + mi * 16 + lr) * 40 + kh * 8];
      a_l[mi] = *(bf16x8*)&Al[(wm * 64 + mi * 16 + lr) * 40 + kh * 8];
    }
#pragma unroll
    for (int nj = 0; nj < 2; ++nj) {
      b1f[nj] = *(bf16x8*)(B1c + boff[nj]);
      b2f[nj] = *(bf16x8*)(B2c + boff[nj]);
    }
#pragma unroll
    for (int mi = 0; mi < 4; ++mi)
#pragma unroll
      for (int nj = 0; nj < 2; ++nj) {
        acc1[mi][nj] = __builtin_amdgcn_mfma_f32_16x16x32_bf16(a_h[mi], b1f[nj], acc1[mi][nj], 0, 0, 0);
        acc1[mi][nj] = __builtin_amdgcn_mfma_f32_16x16x32_bf16(a_l[mi], b1f[nj], acc1[mi][nj], 0, 0, 0);
        acc2[mi][nj] = __builtin_amdgcn_mfma_f32_16x16x32_bf16(a_h[mi], b2f[nj], acc2[mi][nj], 0, 0, 0);
        acc2[mi][nj] = __builtin_amdgcn_mfma_f32_16x16x32_bf16(a_l[mi], b2f[nj], acc2[mi][nj], 0, 0, 0);
      }
    __syncthreads();
  }

#pragma unroll
  for (int mi = 0; mi < 4; ++mi)
#pragma unroll
    for (int nj = 0; nj < 2; ++nj)
#pragma unroll
      for (int r = 0; r < 4; ++r) {
        int row_t = wm * 64 + mi * 16 + kh * 4 + r;
        int gr = rowstart + row_t;
        if (gr < rowend) {
          int col = h0 + wn * 32 + nj * 16 + lr;
          float v1 = acc1[mi][nj][r], v2 = acc2[mi][nj][r];
          float hv = (v1 / (1.f + expf(-v1))) * v2;
          hhi[(size_t)gr * HID + col] = f2bf(hv);
        }
      }
}

// ---------------- GEMM2: pairout = w * (h @ W3) ----------------
// BM=64 BN=64 BK=32 -> 1024 active blocks (4/CU). Same fused B staging from
// w3 f32 [k=H][n=D]. grid: x=col-tile (16), y = e*16+rt.
__global__ __launch_bounds__(256)
void gemm2_mfma(const ushort_t* __restrict__ hhi,
                const float* __restrict__ w3,
                const int* __restrict__ offsets, const float* __restrict__ list_w,
                ushort_t* __restrict__ pairout) {
  __shared__ __align__(16) ushort_t As[64 * 40];
  __shared__ __align__(16) ushort_t Bs[64 * 40];

  const int e = blockIdx.y >> 4;          // 16 row-tiles of 64 per expert
  const int rt = blockIdx.y & 15;
  const int rowstart = offsets[e] + rt * 64;
  const int rowend = offsets[e + 1];
  if (rowstart >= rowend) return;
  const int d0 = blockIdx.x * 64;
  const int tid = threadIdx.x;
  const int lane = tid & 63, wid = tid >> 6;
  const int wm = wid >> 1, wn = wid & 1;
  const int lr = lane & 15, kh = lane >> 4;

  f32x4 acc[2][2];
#pragma unroll
  for (int mi = 0; mi < 2; ++mi)
#pragma unroll
    for (int nj = 0; nj < 2; ++nj) acc[mi][nj] = (f32x4){0.f, 0.f, 0.f, 0.f};

  const int p = tid >> 4, n4 = tid & 15;
  const float* w3e = w3 + (size_t)e * HID * DIM;
  char* Bsc = (char*)Bs;

  // A staging: row = tid>>2, seg = tid&3 (64 rows x 4 uint4)
  const int arow = tid >> 2, aseg = tid & 3;
  int gr = rowstart + arow; if (gr >= rowend) gr = rowstart;
  const size_t asrc = (size_t)gr * HID + aseg * 8;

  int boff[2];
#pragma unroll
  for (int nj = 0; nj < 2; ++nj) {
    int n = wn * 32 + nj * 16 + lr;
    boff[nj] = n * 80 + ((kh * 16) ^ SWZB(n));
  }

  for (int k0 = 0; k0 < HID; k0 += 32) {
    *(uint4*)&As[arow * 40 + aseg * 8] = *(const uint4*)&hhi[asrc + k0];
    {
      const float* r0 = w3e + (size_t)(k0 + 2 * p) * DIM + d0 + n4 * 4;
      float4 v0 = *(const float4*)r0;
      float4 v1 = *(const float4*)(r0 + DIM);
      const float* pv0 = (const float*)&v0;
      const float* pv1 = (const float*)&v1;
#pragma unroll
      for (int c = 0; c < 4; ++c) {
        int n = n4 * 4 + c;
        int off = n * 80 + ((4 * p) ^ SWZB(n));
        *(uint_t*)(Bsc + off) = (uint_t)f2bf(pv0[c]) | ((uint_t)f2bf(pv1[c]) << 16);
      }
    }
    __syncthreads();

    bf16x8 af[2], bf[2];
#pragma unroll
    for (int mi = 0; mi < 2; ++mi)
      af[mi] = *(bf16x8*)&As[(wm * 32 + mi * 16 + lr) * 40 + kh * 8];
#pragma unroll
    for (int nj = 0; nj < 2; ++nj)
      bf[nj] = *(bf16x8*)(Bsc + boff[nj]);
#pragma unroll
    for (int mi = 0; mi < 2; ++mi)
#pragma unroll
      for (int nj = 0; nj < 2; ++nj)
        acc[mi][nj] = __builtin_amdgcn_mfma_f32_16x16x32_bf16(af[mi], bf[nj], acc[mi][nj], 0, 0, 0);
    __syncthreads();
  }

#pragma unroll
  for (int mi = 0; mi < 2; ++mi)
#pragma unroll
    for (int nj = 0; nj < 2; ++nj)
#pragma unroll
      for (int r = 0; r < 4; ++r) {
        int grr = rowstart + wm * 32 + mi * 16 + kh * 4 + r;
        if (grr < rowend) {
          int col = d0 + wn * 32 + nj * 16 + lr;
          pairout[(size_t)grr * DIM + col] = f2bf(acc[mi][nj][r] * list_w[grr]);
        }
      }
}

__global__ void combine_bf(const ushort_t* __restrict__ pairout,
                           const int* __restrict__ pair_pos,
                           float* __restrict__ out) {
  int i = blockIdx.x * 256 + threadIdx.x;
  int t = i >> 8;
  int dv = i & 255;
  int p0 = pair_pos[2 * t], p1 = pair_pos[2 * t + 1];
  ushort4 a = *(const ushort4*)&pairout[(size_t)p0 * DIM + dv * 4];
  ushort4 b = *(const ushort4*)&pairout[(size_t)p1 * DIM + dv * 4];
  float4 o;
  o.x = bf2f(a.x) + bf2f(b.x);
  o.y = bf2f(a.y) + bf2f(b.y);
  o.z = bf2f(a.z) + bf2f(b.z);
  o.w = bf2f(a.w) + bf2f(b.w);
  ((float4*)out)[i] = o;
}

extern "C" void kernel_launch(void* const* d_in, const int* in_sizes, int n_in,
                              void* d_out, int out_size, void* d_ws, size_t ws_size,
                              hipStream_t stream) {
  const float* x   = (const float*)d_in[0];
  const float* rw  = (const float*)d_in[1];
  const float* rb  = (const float*)d_in[2];
  const float* w12 = (const float*)d_in[3];
  const float* w3  = (const float*)d_in[4];
  float* out = (float*)d_out;

  char* ws = (char*)d_ws;
  size_t off = 0;
  auto alloc = [&](size_t bytes) {
    void* p = ws + off;
    off = (off + bytes + 255) & ~255ULL;
    return p;
  };
  int*   counts   = (int*)alloc(NE * 4);
  int*   fill     = (int*)alloc(NE * 4);
  int*   offsets  = (int*)alloc((NE + 1) * 4);
  float* tok_ss   = (float*)alloc(TOK * 4);
  int*   top_e    = (int*)alloc(TOK * 2 * 4);
  float* top_w    = (float*)alloc(TOK * 2 * 4);
  int*   list_tok = (int*)alloc(TOK * 2 * 4);
  float* list_w   = (float*)alloc(TOK * 2 * 4);
  int*   pair_pos = (int*)alloc(TOK * 2 * 4);

  ushort_t* xhi     = (ushort_t*)alloc((size_t)TOK * DIM * 2);        // 4 MB
  ushort_t* xlo     = (ushort_t*)alloc((size_t)TOK * DIM * 2);        // 4 MB
  ushort_t* hhi     = (ushort_t*)alloc((size_t)TOK * 2 * HID * 2);    // 32 MB
  ushort_t* pairoutb= (ushort_t*)alloc((size_t)TOK * 2 * DIM * 2);    // 8 MB

  hipLaunchKernelGGL(zero_kernel, dim3(1), dim3(64), 0, stream, counts);
  hipLaunchKernelGGL(router_kernel, dim3(TOK), dim3(64), 0, stream,
                     x, rw, rb, counts, tok_ss, top_e, top_w);
  hipLaunchKernelGGL(scan_kernel, dim3(1), dim3(64), 0, stream, counts, offsets, fill);
  hipLaunchKernelGGL(assign_kernel, dim3((TOK * 2 + 255) / 256), dim3(256), 0, stream,
                     top_e, top_w, offsets, fill, list_tok, list_w, pair_pos);
  hipLaunchKernelGGL(aux_kernel, dim3(1), dim3(256), 0, stream,
                     tok_ss, out + (size_t)TOK * DIM);

  hipLaunchKernelGGL(convx_kernel, dim3(TOK * DIM / 4 / 256), dim3(256), 0, stream,
                     x, xhi, xlo);
  hipLaunchKernelGGL(gemm1_mfma, dim3(HID / 64, NE * 16), dim3(256), 0, stream,
                     xhi, xlo, w12, offsets, list_tok, hhi);
  hipLaunchKernelGGL(gemm2_mfma, dim3(DIM / 64, NE * 16), dim3(256), 0, stream,
                     hhi, w3, offsets, list_w, pairoutb);
  hipLaunchKernelGGL(combine_bf, dim3(TOK * DIM / 4 / 256), dim3(256), 0, stream,
                     pairoutb, pair_pos, out);
}

// Round 6
// 358.947 us; speedup vs baseline: 5.5900x; 1.4453x over previous
//
#include <hip/hip_runtime.h>
#include <hip/hip_bf16.h>

#define TOK 2048      // B*S
#define DIM 1024      // D
#define HID 4096      // H
#define NE  8         // experts

typedef short bf16x8 __attribute__((ext_vector_type(8)));
typedef float f32x4 __attribute__((ext_vector_type(4)));
typedef unsigned short ushort_t;
typedef unsigned int uint_t;

// XOR-swizzle on 16B slots within a 64B row-payload (rows stride 80B).
#define SWZB(n) (((((n) >> 2) ^ ((n) >> 4)) & 3) << 4)

__device__ __forceinline__ ushort_t f2bf(float f) {
  uint_t b = __float_as_uint(f);
  uint_t r = (b + 0x7FFFu + ((b >> 16) & 1u)) >> 16;
  return (ushort_t)r;
}
__device__ __forceinline__ float bf2f(ushort_t u) {
  return __uint_as_float(((uint_t)u) << 16);
}

// ---------------- router ----------------
__global__ void router_kernel(const float* __restrict__ x,
                              const float* __restrict__ rw,
                              const float* __restrict__ rb,
                              int* __restrict__ counts,
                              float* __restrict__ tok_ss,
                              int* __restrict__ top_e,
                              float* __restrict__ top_w) {
  const int t = blockIdx.x;
  const int lane = threadIdx.x;
  float acc[NE];
#pragma unroll
  for (int e = 0; e < NE; ++e) acc[e] = 0.f;
  const float* xr = x + (size_t)t * DIM;
  for (int d = lane; d < DIM; d += 64) {
    float xv = xr[d];
    const float* w = rw + (size_t)d * NE;
#pragma unroll
    for (int e = 0; e < NE; ++e) acc[e] += xv * w[e];
  }
#pragma unroll
  for (int e = 0; e < NE; ++e) {
    float v = acc[e];
#pragma unroll
    for (int off = 32; off > 0; off >>= 1) v += __shfl_down(v, off, 64);
    acc[e] = v;
  }
  if (lane == 0) {
    float sc[NE];
    float ss = 0.f;
#pragma unroll
    for (int e = 0; e < NE; ++e) {
      float lg = acc[e] + rb[e];
      ss += lg * lg;
      sc[e] = 1.f / (1.f + expf(-lg));
    }
    tok_ss[t] = ss;
    int i0 = 0;
#pragma unroll
    for (int e = 1; e < NE; ++e) if (sc[e] > sc[i0]) i0 = e;
    int i1 = (i0 == 0) ? 1 : 0;
#pragma unroll
    for (int e = 0; e < NE; ++e) if (e != i0 && sc[e] > sc[i1]) i1 = e;
    float s0 = sc[i0], s1 = sc[i1];
    float inv = 1.f / (s0 + s1 + 1e-6f);
    top_e[t * 2 + 0] = i0;
    top_e[t * 2 + 1] = i1;
    top_w[t * 2 + 0] = s0 * inv;
    top_w[t * 2 + 1] = s1 * inv;
    atomicAdd(&counts[i0], 1);
    atomicAdd(&counts[i1], 1);
  }
}

__global__ void zero_kernel(int* __restrict__ counts) {
  if (threadIdx.x < NE) counts[threadIdx.x] = 0;
}

__global__ void scan_kernel(const int* __restrict__ counts,
                            int* __restrict__ offsets,
                            int* __restrict__ fill) {
  if (threadIdx.x == 0) {
    int o = 0;
    for (int e = 0; e < NE; ++e) { offsets[e] = o; o += counts[e]; fill[e] = 0; }
    offsets[NE] = o;
  }
}

__global__ void assign_kernel(const int* __restrict__ top_e,
                              const float* __restrict__ top_w,
                              const int* __restrict__ offsets,
                              int* __restrict__ fill,
                              int* __restrict__ list_tok,
                              float* __restrict__ list_w,
                              int* __restrict__ pair_pos) {
  int i = blockIdx.x * blockDim.x + threadIdx.x;
  if (i >= TOK * 2) return;
  int e = top_e[i];
  int pos = atomicAdd(&fill[e], 1);
  int idx = offsets[e] + pos;
  list_tok[idx] = i >> 1;
  list_w[idx] = top_w[i];
  pair_pos[i] = idx;
}

__global__ void aux_kernel(const float* __restrict__ tok_ss, float* __restrict__ out_aux) {
  __shared__ float sm[256];
  float s = 0.f;
  for (int t = threadIdx.x; t < TOK; t += 256) s += tok_ss[t];
  sm[threadIdx.x] = s;
  __syncthreads();
  for (int w = 128; w > 0; w >>= 1) {
    if (threadIdx.x < w) sm[threadIdx.x] += sm[threadIdx.x + w];
    __syncthreads();
  }
  if (threadIdx.x == 0) *out_aux = 0.01f * sm[0] / (float)(TOK * NE);
}

// ---------------- x f32 -> bf16 ----------------
__global__ void convx_kernel(const float* __restrict__ x, ushort_t* __restrict__ xb) {
  int i = blockIdx.x * 256 + threadIdx.x;
  float4 v = ((const float4*)x)[i];
  ushort4 h;
  h.x = f2bf(v.x);
  h.y = f2bf(v.y);
  h.z = f2bf(v.z);
  h.w = f2bf(v.w);
  ((ushort4*)xb)[i] = h;
}

// ---------------- GEMM1: h = silu(X@W1)*(X@W2) ----------------
// BM=128 BN=64 BK=32, register-prefetched staging. B: w12 f32 read directly,
// converted + transpose-written to LDS [n][k] (stride 40, SWZB swizzle).
__global__ __launch_bounds__(256)
void gemm1_mfma(const ushort_t* __restrict__ xb,
                const float* __restrict__ w12,
                const int* __restrict__ offsets, const int* __restrict__ list_tok,
                ushort_t* __restrict__ hhi) {
  __shared__ __align__(16) ushort_t Ah[128 * 40];
  __shared__ __align__(16) ushort_t B1[64 * 40];
  __shared__ __align__(16) ushort_t B2[64 * 40];
  __shared__ int stok[128];

  const int e = blockIdx.y >> 4;          // 16 row-tiles of 128 per expert
  const int rt = blockIdx.y & 15;
  const int rowstart = offsets[e] + rt * 128;
  const int rowend = offsets[e + 1];
  if (rowstart >= rowend) return;
  const int h0 = blockIdx.x * 64;
  const int tid = threadIdx.x;
  const int lane = tid & 63, wid = tid >> 6;
  const int wm = wid >> 1, wn = wid & 1;
  const int lr = lane & 15, kh = lane >> 4;

  if (tid < 128) {
    int r = rowstart + tid;
    stok[tid] = list_tok[r < rowend ? r : rowstart];
  }
  __syncthreads();

  f32x4 acc1[4][2], acc2[4][2];
#pragma unroll
  for (int mi = 0; mi < 4; ++mi)
#pragma unroll
    for (int nj = 0; nj < 2; ++nj) {
      acc1[mi][nj] = (f32x4){0.f, 0.f, 0.f, 0.f};
      acc2[mi][nj] = (f32x4){0.f, 0.f, 0.f, 0.f};
    }

  // A staging: 128 rows x 4 seg -> 2 slots/thread
  const int arow0 = tid >> 2, aseg = tid & 3;
  const int arow1 = arow0 + 64;
  const size_t asrc0 = (size_t)stok[arow0] * DIM + aseg * 8;
  const size_t asrc1 = (size_t)stok[arow1] * DIM + aseg * 8;
  const int adst0 = arow0 * 40 + aseg * 8;
  const int adst1 = arow1 * 40 + aseg * 8;

  // B staging ids: p = k-pair (k = 2p,2p+1), n4*4 = col base
  const int p = tid >> 4, n4 = tid & 15;
  const float* w12e = w12 + (size_t)e * DIM * (2 * HID) + h0 + n4 * 4;
  char* B1c = (char*)B1;
  char* B2c = (char*)B2;

  int boff[2];
#pragma unroll
  for (int nj = 0; nj < 2; ++nj) {
    int n = wn * 32 + nj * 16 + lr;
    boff[nj] = n * 80 + ((kh * 16) ^ SWZB(n));
  }
  int bwoff[4];
#pragma unroll
  for (int c = 0; c < 4; ++c) {
    int n = n4 * 4 + c;
    bwoff[c] = n * 80 + ((4 * p) ^ SWZB(n));
  }

  uint4 ra0, ra1;
  float4 w1a, w1b, w2a, w2b;
#define G1_LOAD(K0) do { \
    ra0 = *(const uint4*)&xb[asrc0 + (K0)]; \
    ra1 = *(const uint4*)&xb[asrc1 + (K0)]; \
    const float* r0 = w12e + (size_t)((K0) + 2 * p) * (2 * HID); \
    w1a = *(const float4*)r0; \
    w1b = *(const float4*)(r0 + 2 * HID); \
    w2a = *(const float4*)(r0 + HID); \
    w2b = *(const float4*)(r0 + HID + 2 * HID); \
  } while (0)

  G1_LOAD(0);
#pragma unroll 1
  for (int k0 = 0; k0 < DIM; k0 += 32) {
    *(uint4*)&Ah[adst0] = ra0;
    *(uint4*)&Ah[adst1] = ra1;
    {
      const float* p1a = (const float*)&w1a;
      const float* p1b = (const float*)&w1b;
      const float* p2a = (const float*)&w2a;
      const float* p2b = (const float*)&w2b;
#pragma unroll
      for (int c = 0; c < 4; ++c) {
        *(uint_t*)(B1c + bwoff[c]) = (uint_t)f2bf(p1a[c]) | ((uint_t)f2bf(p1b[c]) << 16);
        *(uint_t*)(B2c + bwoff[c]) = (uint_t)f2bf(p2a[c]) | ((uint_t)f2bf(p2b[c]) << 16);
      }
    }
    __syncthreads();
    if (k0 + 32 < DIM) G1_LOAD(k0 + 32);

    bf16x8 af[4], b1f[2], b2f[2];
#pragma unroll
    for (int mi = 0; mi < 4; ++mi)
      af[mi] = *(bf16x8*)&Ah[(wm * 64 + mi * 16 + lr) * 40 + kh * 8];
#pragma unroll
    for (int nj = 0; nj < 2; ++nj) {
      b1f[nj] = *(bf16x8*)(B1c + boff[nj]);
      b2f[nj] = *(bf16x8*)(B2c + boff[nj]);
    }
#pragma unroll
    for (int mi = 0; mi < 4; ++mi)
#pragma unroll
      for (int nj = 0; nj < 2; ++nj) {
        acc1[mi][nj] = __builtin_amdgcn_mfma_f32_16x16x32_bf16(af[mi], b1f[nj], acc1[mi][nj], 0, 0, 0);
        acc2[mi][nj] = __builtin_amdgcn_mfma_f32_16x16x32_bf16(af[mi], b2f[nj], acc2[mi][nj], 0, 0, 0);
      }
    __syncthreads();
  }
#undef G1_LOAD

#pragma unroll
  for (int mi = 0; mi < 4; ++mi)
#pragma unroll
    for (int nj = 0; nj < 2; ++nj)
#pragma unroll
      for (int r = 0; r < 4; ++r) {
        int row_t = wm * 64 + mi * 16 + kh * 4 + r;
        int gr = rowstart + row_t;
        if (gr < rowend) {
          int col = h0 + wn * 32 + nj * 16 + lr;
          float v1 = acc1[mi][nj][r], v2 = acc2[mi][nj][r];
          float hv = (v1 / (1.f + expf(-v1))) * v2;
          hhi[(size_t)gr * HID + col] = f2bf(hv);
        }
      }
}

// ---------------- GEMM2: pairout = w * (h @ W3) ----------------
// BM=64 BN=64 BK=64 (two 32-k sub-stages), register prefetch.
__global__ __launch_bounds__(256)
void gemm2_mfma(const ushort_t* __restrict__ hhi,
                const float* __restrict__ w3,
                const int* __restrict__ offsets, const float* __restrict__ list_w,
                ushort_t* __restrict__ pairout) {
  __shared__ __align__(16) ushort_t As0[64 * 40];
  __shared__ __align__(16) ushort_t As1[64 * 40];
  __shared__ __align__(16) ushort_t Bs0[64 * 40];
  __shared__ __align__(16) ushort_t Bs1[64 * 40];

  const int e = blockIdx.y >> 4;          // 16 row-tiles of 64 per expert
  const int rt = blockIdx.y & 15;
  const int rowstart = offsets[e] + rt * 64;
  const int rowend = offsets[e + 1];
  if (rowstart >= rowend) return;
  const int d0 = blockIdx.x * 64;
  const int tid = threadIdx.x;
  const int lane = tid & 63, wid = tid >> 6;
  const int wm = wid >> 1, wn = wid & 1;
  const int lr = lane & 15, kh = lane >> 4;

  f32x4 acc[2][2];
#pragma unroll
  for (int mi = 0; mi < 2; ++mi)
#pragma unroll
    for (int nj = 0; nj < 2; ++nj) acc[mi][nj] = (f32x4){0.f, 0.f, 0.f, 0.f};

  // A staging: 64 rows x 4 seg -> 1 slot/thread (per 32-k half)
  const int arow = tid >> 2, aseg = tid & 3;
  int gr = rowstart + arow; if (gr >= rowend) gr = rowstart;
  const size_t asrc = (size_t)gr * HID + aseg * 8;
  const int adst = arow * 40 + aseg * 8;

  const int p = tid >> 4, n4 = tid & 15;
  const float* w3e = w3 + (size_t)e * HID * DIM + d0 + n4 * 4;
  char* Bs0c = (char*)Bs0;
  char* Bs1c = (char*)Bs1;

  int boff[2];
#pragma unroll
  for (int nj = 0; nj < 2; ++nj) {
    int n = wn * 32 + nj * 16 + lr;
    boff[nj] = n * 80 + ((kh * 16) ^ SWZB(n));
  }
  int bwoff[4];
#pragma unroll
  for (int c = 0; c < 4; ++c) {
    int n = n4 * 4 + c;
    bwoff[c] = n * 80 + ((4 * p) ^ SWZB(n));
  }

  uint4 ra0, ra1;
  float4 rb00, rb01, rb10, rb11;
#define G2_LOAD(K0) do { \
    ra0 = *(const uint4*)&hhi[asrc + (K0)]; \
    ra1 = *(const uint4*)&hhi[asrc + (K0) + 32]; \
    const float* r0 = w3e + (size_t)((K0) + 2 * p) * DIM; \
    rb00 = *(const float4*)r0; \
    rb01 = *(const float4*)(r0 + DIM); \
    const float* r1 = w3e + (size_t)((K0) + 32 + 2 * p) * DIM; \
    rb10 = *(const float4*)r1; \
    rb11 = *(const float4*)(r1 + DIM); \
  } while (0)

  G2_LOAD(0);
#pragma unroll 1
  for (int k0 = 0; k0 < HID; k0 += 64) {
    *(uint4*)&As0[adst] = ra0;
    *(uint4*)&As1[adst] = ra1;
    {
      const float* pv0 = (const float*)&rb00;
      const float* pv1 = (const float*)&rb01;
      const float* pw0 = (const float*)&rb10;
      const float* pw1 = (const float*)&rb11;
#pragma unroll
      for (int c = 0; c < 4; ++c) {
        *(uint_t*)(Bs0c + bwoff[c]) = (uint_t)f2bf(pv0[c]) | ((uint_t)f2bf(pv1[c]) << 16);
        *(uint_t*)(Bs1c + bwoff[c]) = (uint_t)f2bf(pw0[c]) | ((uint_t)f2bf(pw1[c]) << 16);
      }
    }
    __syncthreads();
    if (k0 + 64 < HID) G2_LOAD(k0 + 64);

    // half 0
    {
      bf16x8 af[2], bf[2];
#pragma unroll
      for (int mi = 0; mi < 2; ++mi)
        af[mi] = *(bf16x8*)&As0[(wm * 32 + mi * 16 + lr) * 40 + kh * 8];
#pragma unroll
      for (int nj = 0; nj < 2; ++nj)
        bf[nj] = *(bf16x8*)(Bs0c + boff[nj]);
#pragma unroll
      for (int mi = 0; mi < 2; ++mi)
#pragma unroll
        for (int nj = 0; nj < 2; ++nj)
          acc[mi][nj] = __builtin_amdgcn_mfma_f32_16x16x32_bf16(af[mi], bf[nj], acc[mi][nj], 0, 0, 0);
    }
    // half 1
    {
      bf16x8 af[2], bf[2];
#pragma unroll
      for (int mi = 0; mi < 2; ++mi)
        af[mi] = *(bf16x8*)&As1[(wm * 32 + mi * 16 + lr) * 40 + kh * 8];
#pragma unroll
      for (int nj = 0; nj < 2; ++nj)
        bf[nj] = *(bf16x8*)(Bs1c + boff[nj]);
#pragma unroll
      for (int mi = 0; mi < 2; ++mi)
#pragma unroll
        for (int nj = 0; nj < 2; ++nj)
          acc[mi][nj] = __builtin_amdgcn_mfma_f32_16x16x32_bf16(af[mi], bf[nj], acc[mi][nj], 0, 0, 0);
    }
    __syncthreads();
  }
#undef G2_LOAD

#pragma unroll
  for (int mi = 0; mi < 2; ++mi)
#pragma unroll
    for (int nj = 0; nj < 2; ++nj)
#pragma unroll
      for (int r = 0; r < 4; ++r) {
        int grr = rowstart + wm * 32 + mi * 16 + kh * 4 + r;
        if (grr < rowend) {
          int col = d0 + wn * 32 + nj * 16 + lr;
          pairout[(size_t)grr * DIM + col] = f2bf(acc[mi][nj][r] * list_w[grr]);
        }
      }
}

__global__ void combine_bf(const ushort_t* __restrict__ pairout,
                           const int* __restrict__ pair_pos,
                           float* __restrict__ out) {
  int i = blockIdx.x * 256 + threadIdx.x;
  int t = i >> 8;
  int dv = i & 255;
  int p0 = pair_pos[2 * t], p1 = pair_pos[2 * t + 1];
  ushort4 a = *(const ushort4*)&pairout[(size_t)p0 * DIM + dv * 4];
  ushort4 b = *(const ushort4*)&pairout[(size_t)p1 * DIM + dv * 4];
  float4 o;
  o.x = bf2f(a.x) + bf2f(b.x);
  o.y = bf2f(a.y) + bf2f(b.y);
  o.z = bf2f(a.z) + bf2f(b.z);
  o.w = bf2f(a.w) + bf2f(b.w);
  ((float4*)out)[i] = o;
}

extern "C" void kernel_launch(void* const* d_in, const int* in_sizes, int n_in,
                              void* d_out, int out_size, void* d_ws, size_t ws_size,
                              hipStream_t stream) {
  const float* x   = (const float*)d_in[0];
  const float* rw  = (const float*)d_in[1];
  const float* rb  = (const float*)d_in[2];
  const float* w12 = (const float*)d_in[3];
  const float* w3  = (const float*)d_in[4];
  float* out = (float*)d_out;

  char* ws = (char*)d_ws;
  size_t off = 0;
  auto alloc = [&](size_t bytes) {
    void* p = ws + off;
    off = (off + bytes + 255) & ~255ULL;
    return p;
  };
  int*   counts   = (int*)alloc(NE * 4);
  int*   fill     = (int*)alloc(NE * 4);
  int*   offsets  = (int*)alloc((NE + 1) * 4);
  float* tok_ss   = (float*)alloc(TOK * 4);
  int*   top_e    = (int*)alloc(TOK * 2 * 4);
  float* top_w    = (float*)alloc(TOK * 2 * 4);
  int*   list_tok = (int*)alloc(TOK * 2 * 4);
  float* list_w   = (float*)alloc(TOK * 2 * 4);
  int*   pair_pos = (int*)alloc(TOK * 2 * 4);

  ushort_t* xb      = (ushort_t*)alloc((size_t)TOK * DIM * 2);        // 4 MB
  ushort_t* hhi     = (ushort_t*)alloc((size_t)TOK * 2 * HID * 2);    // 32 MB
  ushort_t* pairoutb= (ushort_t*)alloc((size_t)TOK * 2 * DIM * 2);    // 8 MB

  hipLaunchKernelGGL(zero_kernel, dim3(1), dim3(64), 0, stream, counts);
  hipLaunchKernelGGL(router_kernel, dim3(TOK), dim3(64), 0, stream,
                     x, rw, rb, counts, tok_ss, top_e, top_w);
  hipLaunchKernelGGL(scan_kernel, dim3(1), dim3(64), 0, stream, counts, offsets, fill);
  hipLaunchKernelGGL(assign_kernel, dim3((TOK * 2 + 255) / 256), dim3(256), 0, stream,
                     top_e, top_w, offsets, fill, list_tok, list_w, pair_pos);
  hipLaunchKernelGGL(aux_kernel, dim3(1), dim3(256), 0, stream,
                     tok_ss, out + (size_t)TOK * DIM);

  hipLaunchKernelGGL(convx_kernel, dim3(TOK * DIM / 4 / 256), dim3(256), 0, stream,
                     x, xb);
  hipLaunchKernelGGL(gemm1_mfma, dim3(HID / 64, NE * 16), dim3(256), 0, stream,
                     xb, w12, offsets, list_tok, hhi);
  hipLaunchKernelGGL(gemm2_mfma, dim3(DIM / 64, NE * 16), dim3(256), 0, stream,
                     hhi, w3, offsets, list_w, pairoutb);
  hipLaunchKernelGGL(combine_bf, dim3(TOK * DIM / 4 / 256), dim3(256), 0, stream,
                     pairoutb, pair_pos, out);
}

// Round 7
// 341.037 us; speedup vs baseline: 5.8835x; 1.0525x over previous
//
#include <hip/hip_runtime.h>
#include <hip/hip_bf16.h>

#define TOK 2048      // B*S
#define DIM 1024      // D
#define HID 4096      // H
#define NE  8         // experts

typedef short bf16x8 __attribute__((ext_vector_type(8)));
typedef float f32x4 __attribute__((ext_vector_type(4)));
typedef unsigned short ushort_t;
typedef unsigned int uint_t;

// XOR-swizzle on 16B slots within a 64B row-payload (rows stride 80B).
#define SWZB(n) (((((n) >> 2) ^ ((n) >> 4)) & 3) << 4)

__device__ __forceinline__ ushort_t f2bf(float f) {
  uint_t b = __float_as_uint(f);
  uint_t r = (b + 0x7FFFu + ((b >> 16) & 1u)) >> 16;
  return (ushort_t)r;
}
__device__ __forceinline__ float bf2f(ushort_t u) {
  return __uint_as_float(((uint_t)u) << 16);
}
// HW packed convert: {bf16(a), bf16(b)} in one VOP3 (RNE, same as f2bf)
__device__ __forceinline__ uint_t pk2bf(float a, float b) {
  uint_t r;
  asm("v_cvt_pk_bf16_f32 %0, %1, %2" : "=v"(r) : "v"(a), "v"(b));
  return r;
}

// ---------------- router ----------------
__global__ void router_kernel(const float* __restrict__ x,
                              const float* __restrict__ rw,
                              const float* __restrict__ rb,
                              int* __restrict__ counts,
                              float* __restrict__ tok_ss,
                              int* __restrict__ top_e,
                              float* __restrict__ top_w) {
  const int t = blockIdx.x;
  const int lane = threadIdx.x;
  float acc[NE];
#pragma unroll
  for (int e = 0; e < NE; ++e) acc[e] = 0.f;
  const float* xr = x + (size_t)t * DIM;
  for (int d = lane; d < DIM; d += 64) {
    float xv = xr[d];
    const float* w = rw + (size_t)d * NE;
#pragma unroll
    for (int e = 0; e < NE; ++e) acc[e] += xv * w[e];
  }
#pragma unroll
  for (int e = 0; e < NE; ++e) {
    float v = acc[e];
#pragma unroll
    for (int off = 32; off > 0; off >>= 1) v += __shfl_down(v, off, 64);
    acc[e] = v;
  }
  if (lane == 0) {
    float sc[NE];
    float ss = 0.f;
#pragma unroll
    for (int e = 0; e < NE; ++e) {
      float lg = acc[e] + rb[e];
      ss += lg * lg;
      sc[e] = 1.f / (1.f + expf(-lg));
    }
    tok_ss[t] = ss;
    int i0 = 0;
#pragma unroll
    for (int e = 1; e < NE; ++e) if (sc[e] > sc[i0]) i0 = e;
    int i1 = (i0 == 0) ? 1 : 0;
#pragma unroll
    for (int e = 0; e < NE; ++e) if (e != i0 && sc[e] > sc[i1]) i1 = e;
    float s0 = sc[i0], s1 = sc[i1];
    float inv = 1.f / (s0 + s1 + 1e-6f);
    top_e[t * 2 + 0] = i0;
    top_e[t * 2 + 1] = i1;
    top_w[t * 2 + 0] = s0 * inv;
    top_w[t * 2 + 1] = s1 * inv;
    atomicAdd(&counts[i0], 1);
    atomicAdd(&counts[i1], 1);
  }
}

__global__ void zero_kernel(int* __restrict__ counts) {
  if (threadIdx.x < NE) counts[threadIdx.x] = 0;
}

// scan + assign fused: single block, 256 threads
__global__ void scan_assign_kernel(const int* __restrict__ counts,
                                   const int* __restrict__ top_e,
                                   const float* __restrict__ top_w,
                                   int* __restrict__ offsets,
                                   int* __restrict__ list_tok,
                                   float* __restrict__ list_w,
                                   int* __restrict__ pair_pos) {
  __shared__ int loff[NE + 1];
  __shared__ int lfill[NE];
  if (threadIdx.x == 0) {
    int o = 0;
    for (int e = 0; e < NE; ++e) { loff[e] = o; lfill[e] = o; o += counts[e]; }
    loff[NE] = o;
  }
  __syncthreads();
  if (threadIdx.x <= NE) offsets[threadIdx.x] = loff[threadIdx.x];
  for (int i = threadIdx.x; i < TOK * 2; i += 256) {
    int e = top_e[i];
    int idx = atomicAdd(&lfill[e], 1);
    list_tok[idx] = i >> 1;
    list_w[idx] = top_w[i];
    pair_pos[i] = idx;
  }
}

__global__ void aux_kernel(const float* __restrict__ tok_ss, float* __restrict__ out_aux) {
  __shared__ float sm[256];
  float s = 0.f;
  for (int t = threadIdx.x; t < TOK; t += 256) s += tok_ss[t];
  sm[threadIdx.x] = s;
  __syncthreads();
  for (int w = 128; w > 0; w >>= 1) {
    if (threadIdx.x < w) sm[threadIdx.x] += sm[threadIdx.x + w];
    __syncthreads();
  }
  if (threadIdx.x == 0) *out_aux = 0.01f * sm[0] / (float)(TOK * NE);
}

// ---------------- x f32 -> bf16 (packed cvt) ----------------
__global__ void convx_kernel(const float* __restrict__ x, ushort_t* __restrict__ xb) {
  int i = blockIdx.x * 256 + threadIdx.x;
  float4 v = ((const float4*)x)[i];
  uint2 u;
  u.x = pk2bf(v.x, v.y);
  u.y = pk2bf(v.z, v.w);
  ((uint2*)xb)[i] = u;
}

// ---------------- GEMM1: h = silu(X@W1)*(X@W2) ----------------
// BM=128 BN=64 BK=32, register-prefetched staging. B: w12 f32 read directly,
// cvt_pk-converted + transpose-written to LDS [n][k] (stride 40, SWZB swizzle).
__global__ __launch_bounds__(256)
void gemm1_mfma(const ushort_t* __restrict__ xb,
                const float* __restrict__ w12,
                const int* __restrict__ offsets, const int* __restrict__ list_tok,
                ushort_t* __restrict__ hhi) {
  __shared__ __align__(16) ushort_t Ah[128 * 40];
  __shared__ __align__(16) ushort_t B1[64 * 40];
  __shared__ __align__(16) ushort_t B2[64 * 40];
  __shared__ int stok[128];

  const int e = blockIdx.y >> 4;          // 16 row-tiles of 128 per expert
  const int rt = blockIdx.y & 15;
  const int rowstart = offsets[e] + rt * 128;
  const int rowend = offsets[e + 1];
  if (rowstart >= rowend) return;
  const int h0 = blockIdx.x * 64;
  const int tid = threadIdx.x;
  const int lane = tid & 63, wid = tid >> 6;
  const int wm = wid >> 1, wn = wid & 1;
  const int lr = lane & 15, kh = lane >> 4;

  if (tid < 128) {
    int r = rowstart + tid;
    stok[tid] = list_tok[r < rowend ? r : rowstart];
  }
  __syncthreads();

  f32x4 acc1[4][2], acc2[4][2];
#pragma unroll
  for (int mi = 0; mi < 4; ++mi)
#pragma unroll
    for (int nj = 0; nj < 2; ++nj) {
      acc1[mi][nj] = (f32x4){0.f, 0.f, 0.f, 0.f};
      acc2[mi][nj] = (f32x4){0.f, 0.f, 0.f, 0.f};
    }

  // A staging: 128 rows x 4 seg -> 2 slots/thread
  const int arow0 = tid >> 2, aseg = tid & 3;
  const int arow1 = arow0 + 64;
  const size_t asrc0 = (size_t)stok[arow0] * DIM + aseg * 8;
  const size_t asrc1 = (size_t)stok[arow1] * DIM + aseg * 8;
  const int adst0 = arow0 * 40 + aseg * 8;
  const int adst1 = arow1 * 40 + aseg * 8;

  // B staging ids: p = k-pair (k = 2p,2p+1), n4*4 = col base
  const int p = tid >> 4, n4 = tid & 15;
  const float* w12e = w12 + (size_t)e * DIM * (2 * HID) + h0 + n4 * 4;
  char* B1c = (char*)B1;
  char* B2c = (char*)B2;

  int boff[2];
#pragma unroll
  for (int nj = 0; nj < 2; ++nj) {
    int n = wn * 32 + nj * 16 + lr;
    boff[nj] = n * 80 + ((kh * 16) ^ SWZB(n));
  }
  int bwoff[4];
#pragma unroll
  for (int c = 0; c < 4; ++c) {
    int n = n4 * 4 + c;
    bwoff[c] = n * 80 + ((4 * p) ^ SWZB(n));
  }

  uint4 ra0, ra1;
  float4 w1a, w1b, w2a, w2b;
#define G1_LOAD(K0) do { \
    ra0 = *(const uint4*)&xb[asrc0 + (K0)]; \
    ra1 = *(const uint4*)&xb[asrc1 + (K0)]; \
    const float* r0 = w12e + (size_t)((K0) + 2 * p) * (2 * HID); \
    w1a = *(const float4*)r0; \
    w1b = *(const float4*)(r0 + 2 * HID); \
    w2a = *(const float4*)(r0 + HID); \
    w2b = *(const float4*)(r0 + HID + 2 * HID); \
  } while (0)

  G1_LOAD(0);
#pragma unroll 1
  for (int k0 = 0; k0 < DIM; k0 += 32) {
    *(uint4*)&Ah[adst0] = ra0;
    *(uint4*)&Ah[adst1] = ra1;
    {
      const float* p1a = (const float*)&w1a;
      const float* p1b = (const float*)&w1b;
      const float* p2a = (const float*)&w2a;
      const float* p2b = (const float*)&w2b;
#pragma unroll
      for (int c = 0; c < 4; ++c) {
        *(uint_t*)(B1c + bwoff[c]) = pk2bf(p1a[c], p1b[c]);
        *(uint_t*)(B2c + bwoff[c]) = pk2bf(p2a[c], p2b[c]);
      }
    }
    __syncthreads();
    if (k0 + 32 < DIM) G1_LOAD(k0 + 32);

    bf16x8 af[4], b1f[2], b2f[2];
#pragma unroll
    for (int mi = 0; mi < 4; ++mi)
      af[mi] = *(bf16x8*)&Ah[(wm * 64 + mi * 16 + lr) * 40 + kh * 8];
#pragma unroll
    for (int nj = 0; nj < 2; ++nj) {
      b1f[nj] = *(bf16x8*)(B1c + boff[nj]);
      b2f[nj] = *(bf16x8*)(B2c + boff[nj]);
    }
#pragma unroll
    for (int mi = 0; mi < 4; ++mi)
#pragma unroll
      for (int nj = 0; nj < 2; ++nj) {
        acc1[mi][nj] = __builtin_amdgcn_mfma_f32_16x16x32_bf16(af[mi], b1f[nj], acc1[mi][nj], 0, 0, 0);
        acc2[mi][nj] = __builtin_amdgcn_mfma_f32_16x16x32_bf16(af[mi], b2f[nj], acc2[mi][nj], 0, 0, 0);
      }
    __syncthreads();
  }
#undef G1_LOAD

#pragma unroll
  for (int mi = 0; mi < 4; ++mi)
#pragma unroll
    for (int nj = 0; nj < 2; ++nj)
#pragma unroll
      for (int r = 0; r < 4; ++r) {
        int row_t = wm * 64 + mi * 16 + kh * 4 + r;
        int gr = rowstart + row_t;
        if (gr < rowend) {
          int col = h0 + wn * 32 + nj * 16 + lr;
          float v1 = acc1[mi][nj][r], v2 = acc2[mi][nj][r];
          float hv = (v1 / (1.f + expf(-v1))) * v2;
          hhi[(size_t)gr * HID + col] = f2bf(hv);
        }
      }
}

// ---------------- GEMM2: pairout = w * (h @ W3) ----------------
// BM=64 BN=64 BK=64 (two 32-k sub-stages), register prefetch, cvt_pk B-stage.
__global__ __launch_bounds__(256)
void gemm2_mfma(const ushort_t* __restrict__ hhi,
                const float* __restrict__ w3,
                const int* __restrict__ offsets, const float* __restrict__ list_w,
                ushort_t* __restrict__ pairout) {
  __shared__ __align__(16) ushort_t As0[64 * 40];
  __shared__ __align__(16) ushort_t As1[64 * 40];
  __shared__ __align__(16) ushort_t Bs0[64 * 40];
  __shared__ __align__(16) ushort_t Bs1[64 * 40];

  const int e = blockIdx.y >> 4;          // 16 row-tiles of 64 per expert
  const int rt = blockIdx.y & 15;
  const int rowstart = offsets[e] + rt * 64;
  const int rowend = offsets[e + 1];
  if (rowstart >= rowend) return;
  const int d0 = blockIdx.x * 64;
  const int tid = threadIdx.x;
  const int lane = tid & 63, wid = tid >> 6;
  const int wm = wid >> 1, wn = wid & 1;
  const int lr = lane & 15, kh = lane >> 4;

  f32x4 acc[2][2];
#pragma unroll
  for (int mi = 0; mi < 2; ++mi)
#pragma unroll
    for (int nj = 0; nj < 2; ++nj) acc[mi][nj] = (f32x4){0.f, 0.f, 0.f, 0.f};

  // A staging: 64 rows x 4 seg -> 1 slot/thread (per 32-k half)
  const int arow = tid >> 2, aseg = tid & 3;
  int gr = rowstart + arow; if (gr >= rowend) gr = rowstart;
  const size_t asrc = (size_t)gr * HID + aseg * 8;
  const int adst = arow * 40 + aseg * 8;

  const int p = tid >> 4, n4 = tid & 15;
  const float* w3e = w3 + (size_t)e * HID * DIM + d0 + n4 * 4;
  char* Bs0c = (char*)Bs0;
  char* Bs1c = (char*)Bs1;

  int boff[2];
#pragma unroll
  for (int nj = 0; nj < 2; ++nj) {
    int n = wn * 32 + nj * 16 + lr;
    boff[nj] = n * 80 + ((kh * 16) ^ SWZB(n));
  }
  int bwoff[4];
#pragma unroll
  for (int c = 0; c < 4; ++c) {
    int n = n4 * 4 + c;
    bwoff[c] = n * 80 + ((4 * p) ^ SWZB(n));
  }

  uint4 ra0, ra1;
  float4 rb00, rb01, rb10, rb11;
#define G2_LOAD(K0) do { \
    ra0 = *(const uint4*)&hhi[asrc + (K0)]; \
    ra1 = *(const uint4*)&hhi[asrc + (K0) + 32]; \
    const float* r0 = w3e + (size_t)((K0) + 2 * p) * DIM; \
    rb00 = *(const float4*)r0; \
    rb01 = *(const float4*)(r0 + DIM); \
    const float* r1 = w3e + (size_t)((K0) + 32 + 2 * p) * DIM; \
    rb10 = *(const float4*)r1; \
    rb11 = *(const float4*)(r1 + DIM); \
  } while (0)

  G2_LOAD(0);
#pragma unroll 1
  for (int k0 = 0; k0 < HID; k0 += 64) {
    *(uint4*)&As0[adst] = ra0;
    *(uint4*)&As1[adst] = ra1;
    {
      const float* pv0 = (const float*)&rb00;
      const float* pv1 = (const float*)&rb01;
      const float* pw0 = (const float*)&rb10;
      const float* pw1 = (const float*)&rb11;
#pragma unroll
      for (int c = 0; c < 4; ++c) {
        *(uint_t*)(Bs0c + bwoff[c]) = pk2bf(pv0[c], pv1[c]);
        *(uint_t*)(Bs1c + bwoff[c]) = pk2bf(pw0[c], pw1[c]);
      }
    }
    __syncthreads();
    if (k0 + 64 < HID) G2_LOAD(k0 + 64);

    // half 0
    {
      bf16x8 af[2], bf[2];
#pragma unroll
      for (int mi = 0; mi < 2; ++mi)
        af[mi] = *(bf16x8*)&As0[(wm * 32 + mi * 16 + lr) * 40 + kh * 8];
#pragma unroll
      for (int nj = 0; nj < 2; ++nj)
        bf[nj] = *(bf16x8*)(Bs0c + boff[nj]);
#pragma unroll
      for (int mi = 0; mi < 2; ++mi)
#pragma unroll
        for (int nj = 0; nj < 2; ++nj)
          acc[mi][nj] = __builtin_amdgcn_mfma_f32_16x16x32_bf16(af[mi], bf[nj], acc[mi][nj], 0, 0, 0);
    }
    // half 1
    {
      bf16x8 af[2], bf[2];
#pragma unroll
      for (int mi = 0; mi < 2; ++mi)
        af[mi] = *(bf16x8*)&As1[(wm * 32 + mi * 16 + lr) * 40 + kh * 8];
#pragma unroll
      for (int nj = 0; nj < 2; ++nj)
        bf[nj] = *(bf16x8*)(Bs1c + boff[nj]);
#pragma unroll
      for (int mi = 0; mi < 2; ++mi)
#pragma unroll
        for (int nj = 0; nj < 2; ++nj)
          acc[mi][nj] = __builtin_amdgcn_mfma_f32_16x16x32_bf16(af[mi], bf[nj], acc[mi][nj], 0, 0, 0);
    }
    __syncthreads();
  }
#undef G2_LOAD

#pragma unroll
  for (int mi = 0; mi < 2; ++mi)
#pragma unroll
    for (int nj = 0; nj < 2; ++nj)
#pragma unroll
      for (int r = 0; r < 4; ++r) {
        int grr = rowstart + wm * 32 + mi * 16 + kh * 4 + r;
        if (grr < rowend) {
          int col = d0 + wn * 32 + nj * 16 + lr;
          pairout[(size_t)grr * DIM + col] = f2bf(acc[mi][nj][r] * list_w[grr]);
        }
      }
}

__global__ void combine_bf(const ushort_t* __restrict__ pairout,
                           const int* __restrict__ pair_pos,
                           float* __restrict__ out) {
  int i = blockIdx.x * 256 + threadIdx.x;
  int t = i >> 8;
  int dv = i & 255;
  int p0 = pair_pos[2 * t], p1 = pair_pos[2 * t + 1];
  ushort4 a = *(const ushort4*)&pairout[(size_t)p0 * DIM + dv * 4];
  ushort4 b = *(const ushort4*)&pairout[(size_t)p1 * DIM + dv * 4];
  float4 o;
  o.x = bf2f(a.x) + bf2f(b.x);
  o.y = bf2f(a.y) + bf2f(b.y);
  o.z = bf2f(a.z) + bf2f(b.z);
  o.w = bf2f(a.w) + bf2f(b.w);
  ((float4*)out)[i] = o;
}

extern "C" void kernel_launch(void* const* d_in, const int* in_sizes, int n_in,
                              void* d_out, int out_size, void* d_ws, size_t ws_size,
                              hipStream_t stream) {
  const float* x   = (const float*)d_in[0];
  const float* rw  = (const float*)d_in[1];
  const float* rb  = (const float*)d_in[2];
  const float* w12 = (const float*)d_in[3];
  const float* w3  = (const float*)d_in[4];
  float* out = (float*)d_out;

  char* ws = (char*)d_ws;
  size_t off = 0;
  auto alloc = [&](size_t bytes) {
    void* p = ws + off;
    off = (off + bytes + 255) & ~255ULL;
    return p;
  };
  int*   counts   = (int*)alloc(NE * 4);
  int*   offsets  = (int*)alloc((NE + 1) * 4);
  float* tok_ss   = (float*)alloc(TOK * 4);
  int*   top_e    = (int*)alloc(TOK * 2 * 4);
  float* top_w    = (float*)alloc(TOK * 2 * 4);
  int*   list_tok = (int*)alloc(TOK * 2 * 4);
  float* list_w   = (float*)alloc(TOK * 2 * 4);
  int*   pair_pos = (int*)alloc(TOK * 2 * 4);

  ushort_t* xb      = (ushort_t*)alloc((size_t)TOK * DIM * 2);        // 4 MB
  ushort_t* hhi     = (ushort_t*)alloc((size_t)TOK * 2 * HID * 2);    // 32 MB
  ushort_t* pairoutb= (ushort_t*)alloc((size_t)TOK * 2 * DIM * 2);    // 8 MB

  hipLaunchKernelGGL(zero_kernel, dim3(1), dim3(64), 0, stream, counts);
  hipLaunchKernelGGL(router_kernel, dim3(TOK), dim3(64), 0, stream,
                     x, rw, rb, counts, tok_ss, top_e, top_w);
  hipLaunchKernelGGL(scan_assign_kernel, dim3(1), dim3(256), 0, stream,
                     counts, top_e, top_w, offsets, list_tok, list_w, pair_pos);
  hipLaunchKernelGGL(aux_kernel, dim3(1), dim3(256), 0, stream,
                     tok_ss, out + (size_t)TOK * DIM);

  hipLaunchKernelGGL(convx_kernel, dim3(TOK * DIM / 4 / 256), dim3(256), 0, stream,
                     x, xb);
  hipLaunchKernelGGL(gemm1_mfma, dim3(HID / 64, NE * 16), dim3(256), 0, stream,
                     xb, w12, offsets, list_tok, hhi);
  hipLaunchKernelGGL(gemm2_mfma, dim3(DIM / 64, NE * 16), dim3(256), 0, stream,
                     hhi, w3, offsets, list_w, pairoutb);
  hipLaunchKernelGGL(combine_bf, dim3(TOK * DIM / 4 / 256), dim3(256), 0, stream,
                     pairoutb, pair_pos, out);
}